// Round 5
// baseline (143905.920 us; speedup 1.0000x reference)
//
#include <hip/hip_runtime.h>

#define B_    128
#define T_    200
#define TE_   256
#define H_    256
#define PRE_  128
#define OUT_  400
#define BT_   (B_*T_)          // 25600

__device__ __forceinline__ float sigm_(float x){ return 1.f/(1.f+__expf(-x)); }
__device__ __forceinline__ float tanh_(float x){
  x = fminf(15.f, fmaxf(-15.f, x));
  float e = __expf(2.f*x);
  return 1.f - 2.f/(e+1.f);
}
__device__ __forceinline__ float b2f_lo(unsigned u){ return __uint_as_float(u << 16); }
__device__ __forceinline__ float b2f_hi(unsigned u){ return __uint_as_float(u & 0xffff0000u); }
__device__ __forceinline__ unsigned short f2b(float f){
  unsigned u = __float_as_uint(f);
  unsigned r = (u + 0x7fff + ((u >> 16) & 1)) >> 16;   // RNE
  return (unsigned short)r;
}

// ---------------------------------------------------------------------------
// packed-weight geometry (all bf16):
//  TRIPLE slice (768-out matvec, one wave-slot): [32 oct][3 g][64 lane][8 k]
//     -> 96 KB = 6144 uint4; lane entry at  oct*192 + g*64 + lane   (uint4)
//  SINGLE slice (256-out matvec, one wave-slot): [32 oct][64 lane][8 k]
//     -> 32 KB = 2048 uint4; lane entry at  oct*64 + lane
// Wpk layout (uint4 offsets):
//  awihA 0 | awhh 24576 | g1whh 49152 | g2whh 73728   (4 slots x 6144 each)
//  wq 98304 | wpA 106496 | wpB 114688                 (4 slots x 2048 each)
//  g1wih 122880 | g2wih 147456                        (4 slots x 6144 each)
// ---------------------------------------------------------------------------

__device__ __forceinline__ void fma8(float& a, const uint4 w, const float4 xa, const float4 xb){
  a = fmaf(xa.x, b2f_lo(w.x), a); a = fmaf(xa.y, b2f_hi(w.x), a);
  a = fmaf(xa.z, b2f_lo(w.y), a); a = fmaf(xa.w, b2f_hi(w.y), a);
  a = fmaf(xb.x, b2f_lo(w.z), a); a = fmaf(xb.y, b2f_hi(w.z), a);
  a = fmaf(xb.z, b2f_lo(w.w), a); a = fmaf(xb.w, b2f_hi(w.w), a);
}

#define MV3_PF 4
// triple matvec: lane owns output cols {c, c+256, c+512}; K=256 serial.
__device__ __forceinline__ void mv3_32(const uint4* __restrict__ seg, const float* __restrict__ x,
                                       int l, float& o0, float& o1, float& o2)
{
  const uint4* p = seg + l;
  uint4 st[MV3_PF][3];
#pragma unroll
  for (int i = 0; i < MV3_PF; ++i){ st[i][0]=p[i*192]; st[i][1]=p[i*192+64]; st[i][2]=p[i*192+128]; }
  float a0=0.f, a1=0.f, a2=0.f;
#pragma unroll
  for (int oct = 0; oct < 32; ++oct){
    uint4 w0 = st[oct%MV3_PF][0], w1 = st[oct%MV3_PF][1], w2 = st[oct%MV3_PF][2];
    if (oct + MV3_PF < 32){
      const uint4* q = p + (oct+MV3_PF)*192;
      st[oct%MV3_PF][0] = q[0]; st[oct%MV3_PF][1] = q[64]; st[oct%MV3_PF][2] = q[128];
    }
    float4 xa = *(const float4*)(x + oct*8);
    float4 xb = *(const float4*)(x + oct*8 + 4);
    fma8(a0, w0, xa, xb); fma8(a1, w1, xa, xb); fma8(a2, w2, xa, xb);
  }
  o0=a0; o1=a1; o2=a2;
}

#define MV1_PF 8
// single matvec: lane owns output col c; K=256 serial; 2 interleaved accs.
__device__ __forceinline__ float mv1_32(const uint4* __restrict__ seg, const float* __restrict__ x, int l)
{
  const uint4* p = seg + l;
  uint4 st[MV1_PF];
#pragma unroll
  for (int i = 0; i < MV1_PF; ++i) st[i] = p[i*64];
  float a0=0.f, a1=0.f;
#pragma unroll
  for (int oct = 0; oct < 32; ++oct){
    uint4 wv = st[oct%MV1_PF];
    if (oct + MV1_PF < 32) st[oct%MV1_PF] = p[(oct+MV1_PF)*64];
    float4 xa = *(const float4*)(x + oct*8);
    float4 xb = *(const float4*)(x + oct*8 + 4);
    a0 = fmaf(xa.x, b2f_lo(wv.x), a0); a1 = fmaf(xa.y, b2f_hi(wv.x), a1);
    a0 = fmaf(xa.z, b2f_lo(wv.y), a0); a1 = fmaf(xa.w, b2f_hi(wv.y), a1);
    a0 = fmaf(xb.x, b2f_lo(wv.z), a0); a1 = fmaf(xb.y, b2f_hi(wv.z), a1);
    a0 = fmaf(xb.z, b2f_lo(wv.w), a0); a1 = fmaf(xb.w, b2f_hi(wv.w), a1);
  }
  return a0 + a1;
}

// scores: lane owns te-col; e = sum_h v[h]*tanh(pm[h][te]+q[h])
__device__ __forceinline__ float mvtanh_32(const uint4* __restrict__ seg,
                                           const float* __restrict__ q, const float* __restrict__ v, int l)
{
  const uint4* p = seg + l;
  uint4 st[MV1_PF];
#pragma unroll
  for (int i = 0; i < MV1_PF; ++i) st[i] = p[i*64];
  float a0=0.f, a1=0.f;
#pragma unroll
  for (int oct = 0; oct < 32; ++oct){
    uint4 wv = st[oct%MV1_PF];
    if (oct + MV1_PF < 32) st[oct%MV1_PF] = p[(oct+MV1_PF)*64];
    float4 qa = *(const float4*)(q + oct*8), qb = *(const float4*)(q + oct*8 + 4);
    float4 va = *(const float4*)(v + oct*8), vb = *(const float4*)(v + oct*8 + 4);
    a0 = fmaf(va.x, tanh_(b2f_lo(wv.x)+qa.x), a0); a1 = fmaf(va.y, tanh_(b2f_hi(wv.x)+qa.y), a1);
    a0 = fmaf(va.z, tanh_(b2f_lo(wv.y)+qa.z), a0); a1 = fmaf(va.w, tanh_(b2f_hi(wv.y)+qa.w), a1);
    a0 = fmaf(vb.x, tanh_(b2f_lo(wv.z)+qb.x), a0); a1 = fmaf(vb.y, tanh_(b2f_hi(wv.z)+qb.y), a1);
    a0 = fmaf(vb.z, tanh_(b2f_lo(wv.w)+qb.z), a0); a1 = fmaf(vb.w, tanh_(b2f_hi(wv.w)+qb.w), a1);
  }
  return a0 + a1;
}

// ---------------- fp32 transpose (prologue/epilogue GEMM weights) ----------------
struct TD { const float* src; float* dst; int N; int Ksrc; int col0; int Keff; int blk0; };
struct TDs { TD d[5]; };

__global__ __launch_bounds__(256) void transpose_cast(TDs P)
{
  int bid = blockIdx.x, m = 0;
#pragma unroll
  for (int i = 1; i < 5; ++i) if (bid >= P.d[i].blk0) m = i;
  TD t = P.d[m];
  long gid = (long)(bid - t.blk0)*256 + threadIdx.x;
  long nk = (long)t.N * t.Keff;
  if (gid >= nk) return;
  int k = (int)(gid / t.N);
  int j = (int)(gid % t.N);
  t.dst[(size_t)k*t.N + j] = t.src[(size_t)j*t.Ksrc + t.col0 + k];
}

// ---------------- bf16 weight repack into per-wave slices ----------------
struct WP { const float* src; int dstoff_u4; int fmt3; int col0; int srcK; int blk0; };
struct WPs { WP d[9]; };

__global__ __launch_bounds__(256) void wpack(WPs P, unsigned short* __restrict__ dst)
{
  int bid = blockIdx.x, m = 0;
#pragma unroll
  for (int i = 1; i < 9; ++i) if (bid >= P.d[i].blk0) m = i;
  WP t = P.d[m];
  int idx = (bid - t.blk0)*256 + threadIdx.x;
  int total = t.fmt3 ? 196608 : 65536;
  if (idx >= total) return;
  int kk = idx & 7, l = (idx >> 3) & 63;
  int j, k;
  if (t.fmt3){
    int g   = (idx >> 9) % 3;
    int oct = (idx / 1536) & 31;
    int s   = idx / 49152;
    j = g*256 + s*64 + l; k = oct*8 + kk;
  } else {
    int oct = (idx >> 9) & 31;
    int s   = idx >> 14;
    j = s*64 + l; k = oct*8 + kk;
  }
  dst[(size_t)t.dstoff_u4*8 + idx] = f2b(t.src[(size_t)j*t.srcK + t.col0 + k]);
}

// ---------------- enc repack: [b][slot h/64][oct te/8][64 h][8 te] bf16 ----------------
__global__ __launch_bounds__(256) void encpack(const float* __restrict__ enc, unsigned short* __restrict__ dst)
{
  size_t gid = (size_t)blockIdx.x*256 + threadIdx.x;   // 128*256*256
  int b  = (int)(gid >> 16);
  int te = (int)(gid >> 8) & 255;
  int h  = (int)gid & 255;
  float v = enc[gid];
  dst[(size_t)b*65536 + ((((h>>6)*32) + (te>>3)) << 9) + ((h&63) << 3) + (te&7)] = f2b(v);
}

// ---------------- generic tiled GEMM: C = act(A[M,K] @ WT[K,N] + bias) ----------------
// AMODE: 0 = plain fp32 (lda), 1 = teacher-forced prev-frame loader
// OUTMODE: 0 = fp32 row-major, 3 = pm packed-slice bf16 store
template<int AMODE, bool RELU, int OUTMODE>
__global__ __launch_bounds__(256) void gemm_k(const float* __restrict__ A, int lda,
                                              const float* __restrict__ WT, int N, int K,
                                              const float* __restrict__ bias,
                                              float* __restrict__ C)
{
  const int tid  = threadIdx.x;
  const int row0 = blockIdx.x * 64;
  const int n0   = blockIdx.y * 64;
  __shared__ float As[16][68];
  __shared__ float Bs[16][64];
  const int tx = tid & 15, ty = tid >> 4;
  float acc[4][4];
#pragma unroll
  for (int i = 0; i < 4; ++i)
#pragma unroll
    for (int j = 0; j < 4; ++j) acc[i][j] = 0.f;

  for (int k0 = 0; k0 < K; k0 += 16){
#pragma unroll
    for (int ll = 0; ll < 4; ++ll){
      int idx = tid + ll*256;
      int m2 = idx >> 4, kk = idx & 15;
      float v;
      if (AMODE == 1){
        int r = row0 + m2;
        int t = r % T_;
        v = (t == 0) ? 0.f : A[(size_t)(r-1)*OUT_ + k0 + kk];
      } else {
        v = A[(size_t)(row0+m2)*lda + k0 + kk];
      }
      As[kk][m2] = v;
    }
#pragma unroll
    for (int ll = 0; ll < 4; ++ll){
      int idx = tid + ll*256;
      int kk = idx >> 6, j = idx & 63;
      int jg = n0 + j;
      Bs[kk][j] = (jg < N) ? WT[(size_t)(k0+kk)*N + jg] : 0.f;
    }
    __syncthreads();
#pragma unroll
    for (int kk = 0; kk < 16; ++kk){
      float4 a4 = *(const float4*)&As[kk][ty*4];
      float4 b4 = *(const float4*)&Bs[kk][tx*4];
      acc[0][0] = fmaf(a4.x, b4.x, acc[0][0]); acc[0][1] = fmaf(a4.x, b4.y, acc[0][1]);
      acc[0][2] = fmaf(a4.x, b4.z, acc[0][2]); acc[0][3] = fmaf(a4.x, b4.w, acc[0][3]);
      acc[1][0] = fmaf(a4.y, b4.x, acc[1][0]); acc[1][1] = fmaf(a4.y, b4.y, acc[1][1]);
      acc[1][2] = fmaf(a4.y, b4.z, acc[1][2]); acc[1][3] = fmaf(a4.y, b4.w, acc[1][3]);
      acc[2][0] = fmaf(a4.z, b4.x, acc[2][0]); acc[2][1] = fmaf(a4.z, b4.y, acc[2][1]);
      acc[2][2] = fmaf(a4.z, b4.z, acc[2][2]); acc[2][3] = fmaf(a4.z, b4.w, acc[2][3]);
      acc[3][0] = fmaf(a4.w, b4.x, acc[3][0]); acc[3][1] = fmaf(a4.w, b4.y, acc[3][1]);
      acc[3][2] = fmaf(a4.w, b4.z, acc[3][2]); acc[3][3] = fmaf(a4.w, b4.w, acc[3][3]);
    }
    __syncthreads();
  }
#pragma unroll
  for (int i = 0; i < 4; ++i){
    int r = row0 + ty*4 + i;
#pragma unroll
    for (int jj = 0; jj < 4; ++jj){
      int c = n0 + tx*4 + jj;
      if (c < N){
        float v = acc[i][jj] + (bias ? bias[c] : 0.f);
        if (RELU) v = fmaxf(v, 0.f);
        if (OUTMODE == 0){
          C[(size_t)r*N + c] = v;
        } else {
          int bb = r >> 8, te = r & 255, h = c;
          ((unsigned short*)C)[(size_t)bb*65536 + ((((te>>6)*32) + (h>>3)) << 9)
                               + ((te&63) << 3) + (h&7)] = f2b(v);
        }
      }
    }
  }
}

// ---------------- persistent per-batch decoder (1024 threads, 16 waves) ----------------
struct DP {
  const float *preGI;
  const uint4 *wpk, *pmpk, *encpk;
  const float *abhh, *g1bih, *g1bhh, *g2bih, *g2bhh, *bp, *v_attn;
  float *decbuf, *aln;
};

__global__ __launch_bounds__(1024, 4) void decoder_kernel(DP P)
{
  const int tid = threadIdx.x;
  const int b = blockIdx.x;
  const int w = tid >> 6, l = tid & 63;

  __shared__ __align__(16) float s_gi[768], s_gh[768], s_g1h[768], s_g2h[768];
  __shared__ __align__(16) float s_ah[256], s_h1[256], s_h2[256], s_av[256];
  __shared__ __align__(16) float s_q[256], s_dq[256], s_dec[256], s_dec2[256];
  __shared__ __align__(16) float s_v[256], s_e[256], s_alx[256];
  __shared__ float s_red[4];

  // ---- per-wave stream segment pointers ----
  const uint4* segP1 = P.wpk + (size_t)w*6144;   // P1 slot (awihA w0-3 | awhh w4-7 | g1whh w8-11 | g2whh w12-15)
  const uint4* segB   = nullptr;   // g1wih (w0-3) / g2wih (w4-7)
  const uint4* segWQ  = nullptr;   // wq (w8-11)
  const uint4* segPM  = nullptr;   // pm slice (w8-11)
  const uint4* segWPB = nullptr;   // wpB (w8-11)
  const uint4* segWPA = nullptr;   // wpA (w12-15)
  const uint4* segENC = nullptr;   // enc slice (w12-15)
  if (w < 4)            segB   = P.wpk + 122880 + (size_t)w*6144;
  else if (w < 8)       segB   = P.wpk + 147456 + (size_t)(w-4)*6144;
  else if (w < 12){
    segWQ  = P.wpk + 98304  + (size_t)(w-8)*2048;
    segWPB = P.wpk + 114688 + (size_t)(w-8)*2048;
    segPM  = P.pmpk + (size_t)b*8192 + (size_t)(w-8)*2048;
  } else {
    segWPA = P.wpk + 106496 + (size_t)(w-12)*2048;
    segENC = P.encpk + (size_t)b*8192 + (size_t)(w-12)*2048;
  }

  // ---- role biases to registers ----
  float bA0=0.f, bA1=0.f, bA2=0.f;       // P1 gh pre-act bias
  float bI0=0.f, bI1=0.f, bI2=0.f;       // gih bias (P6b / P7)
  float bP = 0.f;
  if (w >= 4 && w < 8){  int c = 64*(w-4)+l;  bA0=P.abhh[c];  bA1=P.abhh[256+c];  bA2=P.abhh[512+c];
                         bI0=P.g2bih[c]; bI1=P.g2bih[256+c]; bI2=P.g2bih[512+c]; }
  if (w >= 8 && w < 12){ int c = 64*(w-8)+l;  bA0=P.g1bhh[c]; bA1=P.g1bhh[256+c]; bA2=P.g1bhh[512+c];
                         bP = P.bp[c]; }
  if (w >= 12){          int c = 64*(w-12)+l; bA0=P.g2bhh[c]; bA1=P.g2bhh[256+c]; bA2=P.g2bhh[512+c]; }
  if (w < 4){            int c = 64*w+l;      bI0=P.g1bih[c]; bI1=P.g1bih[256+c]; bI2=P.g1bih[512+c]; }

  if (tid < 256){
    s_ah[tid]=0.f; s_h1[tid]=0.f; s_h2[tid]=0.f; s_av[tid]=0.f;
    s_v[tid] = P.v_attn[tid];
  }
  __syncthreads();

  const float* pregb = P.preGI + (size_t)b*T_*768;
  float* aln_b = P.aln    + (size_t)b*T_*TE_;
  float* dec_b = P.decbuf + (size_t)b*T_*H_;

  for (int t = 0; t < T_; ++t){
    // teacher-forced gate-input prefetch (consumed in C1)
    float pr0=0.f, pr1=0.f, pr2=0.f;
    if (tid < 256){
      const float* pg = pregb + (size_t)t*768 + tid;
      pr0 = pg[0]; pr1 = pg[256]; pr2 = pg[512];
    }

    // ==== P1: four 768-wide recurrent matvecs (col-triple per lane) ====
    {
      const float* x = (w < 4) ? s_av : (w < 8) ? s_ah : (w < 12) ? s_h1 : s_h2;
      float a0, a1, a2;
      mv3_32(segP1, x, l, a0, a1, a2);
      int c = 64*(w & 3) + l;
      if (w < 4){        s_gi[c]=a0;      s_gi[256+c]=a1;      s_gi[512+c]=a2; }
      else if (w < 8){   s_gh[c]=a0+bA0;  s_gh[256+c]=a1+bA1;  s_gh[512+c]=a2+bA2; }
      else if (w < 12){  s_g1h[c]=a0+bA0; s_g1h[256+c]=a1+bA1; s_g1h[512+c]=a2+bA2; }
      else {             s_g2h[c]=a0+bA0; s_g2h[256+c]=a1+bA1; s_g2h[512+c]=a2+bA2; }
    }
    __syncthreads();                                   // B1
    // ==== C1: attention-GRU gate ====
    if (tid < 256){
      float gi0 = s_gi[tid] + pr0, gi1 = s_gi[256+tid] + pr1, gi2 = s_gi[512+tid] + pr2;
      float gh0 = s_gh[tid], gh1 = s_gh[256+tid], gh2 = s_gh[512+tid];
      float r = sigm_(gi0+gh0), z = sigm_(gi1+gh1), n = tanh_(gi2 + r*gh2);
      s_ah[tid] = (1.f-z)*n + z*s_ah[tid];
    }
    __syncthreads();                                   // B2
    // ==== P2: wq@ah (w8-11) and wpA@ah (w12-15) ====
    if (w >= 12)      s_dq[64*(w-12)+l] = mv1_32(segWPA, s_ah, l);
    else if (w >= 8)  s_q [64*(w-8)+l]  = mv1_32(segWQ,  s_ah, l);
    __syncthreads();                                   // B3
    // ==== P3: scores (w8-11) ====
    if (w >= 8 && w < 12)
      s_e[64*(w-8)+l] = mvtanh_32(segPM, s_q, s_v, l);
    __syncthreads();                                   // B4
    // ==== SM: exp + partial sums (w12-15) ====
    if (w >= 12){
      int te = 64*(w-12)+l;
      float ex = __expf(s_e[te]);
      s_alx[te] = ex;
      float s = ex;
      for (int o = 32; o; o >>= 1) s += __shfl_down(s, o, 64);
      if (l == 0) s_red[w-12] = s;
    }
    __syncthreads();                                   // B5
    // ==== P5: context (w12-15) + alignment store (w0-3) ====
    {
      float inv_tot = 1.f / ((s_red[0]+s_red[1]) + (s_red[2]+s_red[3]));
      if (w >= 12){
        float a = mv1_32(segENC, s_alx, l);
        s_av[64*(w-12)+l] = a * inv_tot;
      } else if (w < 4){
        int te = 64*w + l;
        aln_b[(size_t)t*TE_ + te] = s_alx[te] * inv_tot;
      }
    }
    __syncthreads();                                   // B6
    // ==== P6a: dec = dq + wpB@av + bp (w8-11) ====
    if (w >= 8 && w < 12){
      float a = mv1_32(segWPB, s_av, l);
      int c = 64*(w-8)+l;
      s_dec[c] = s_dq[c] + a + bP;
    }
    __syncthreads();                                   // B7
    // ==== P6b: decoder GRU1 + residual (w0-3) ====
    if (w < 4){
      float a0, a1, a2;
      mv3_32(segB, s_dec, l, a0, a1, a2);
      int c = 64*w + l;
      float gi0 = a0+bI0, gi1 = a1+bI1, gi2 = a2+bI2;
      float r = sigm_(gi0 + s_g1h[c]), z = sigm_(gi1 + s_g1h[256+c]);
      float n = tanh_(gi2 + r*s_g1h[512+c]);
      float h1n = (1.f-z)*n + z*s_h1[c];
      s_h1[c] = h1n;
      s_dec2[c] = s_dec[c] + h1n;
    }
    __syncthreads();                                   // B8
    // ==== P7: decoder GRU2 + residual + store (w4-7) ====
    if (w >= 4 && w < 8){
      float a0, a1, a2;
      mv3_32(segB, s_dec2, l, a0, a1, a2);
      int c = 64*(w-4) + l;
      float gi0 = a0+bI0, gi1 = a1+bI1, gi2 = a2+bI2;
      float r = sigm_(gi0 + s_g2h[c]), z = sigm_(gi1 + s_g2h[256+c]);
      float n = tanh_(gi2 + r*s_g2h[512+c]);
      float h2n = (1.f-z)*n + z*s_h2[c];
      s_h2[c] = h2n;
      dec_b[(size_t)t*H_ + c] = s_dec2[c] + h2n;
    }
    __syncthreads();                                   // B9
  }
}

// ---------------- host ----------------
extern "C" void kernel_launch(void* const* d_in, const int* in_sizes, int n_in,
                              void* d_out, int out_size, void* d_ws, size_t ws_size,
                              hipStream_t stream)
{
  const float* enc   = (const float*)d_in[0];
  const float* tgt   = (const float*)d_in[1];
  const float* pw1   = (const float*)d_in[2];
  const float* pb1   = (const float*)d_in[3];
  const float* pw2   = (const float*)d_in[4];
  const float* pb2   = (const float*)d_in[5];
  const float* awih  = (const float*)d_in[6];
  const float* awhh  = (const float*)d_in[7];
  const float* abih  = (const float*)d_in[8];
  const float* abhh  = (const float*)d_in[9];
  const float* wq    = (const float*)d_in[10];
  const float* wm    = (const float*)d_in[11];
  const float* vat   = (const float*)d_in[12];
  const float* wp    = (const float*)d_in[13];
  const float* bp    = (const float*)d_in[14];
  const float* g1wih = (const float*)d_in[15];
  const float* g1whh = (const float*)d_in[16];
  const float* g1bih = (const float*)d_in[17];
  const float* g1bhh = (const float*)d_in[18];
  const float* g2wih = (const float*)d_in[19];
  const float* g2whh = (const float*)d_in[20];
  const float* g2bih = (const float*)d_in[21];
  const float* g2bhh = (const float*)d_in[22];
  const float* wo    = (const float*)d_in[23];
  const float* bo    = (const float*)d_in[24];

  float* ws = (float*)d_ws;
  size_t off = 0;
  auto alloc = [&](size_t n){ float* p = ws + off; off += (n + 3) & ~(size_t)3; return p; };

  // fp32 transposed weights (prologue/epilogue GEMMs)
  float* wmT    = alloc(65536);
  float* w1T    = alloc(102400);
  float* w2T    = alloc(32768);
  float* awihPT = alloc(98304);
  float* woT    = alloc(102400);
  // packed bf16 streams
  float* wpkf   = alloc(688128);                 // 172032 uint4
  float* pmpkf  = alloc(4194304);                // 128 * 8192 uint4
  float* encpkf = alloc(4194304);
  // fp32 activation buffers
  float* decb   = alloc((size_t)BT_*H_);         // also prenet-1 output (aliased lifetimes)
  float* p2f    = alloc((size_t)BT_*PRE_);
  float* preGIf = alloc((size_t)BT_*3*H_);
  float* p1f = decb;

  // ---- 1. fp32 transposes ----
  TDs td;
  const float* tsr[5] = { wm,  pw1, pw2, awih, wo  };
  float* tds[5]       = { wmT, w1T, w2T, awihPT, woT };
  int   tN[5]  = { 256, 256, 128, 768, 400 };
  int   tK[5]  = { 256, 400, 256, 384, 256 };
  int   tc[5]  = { 0,   0,   0,   0,   0   };
  int   tE[5]  = { 256, 400, 256, 128, 256 };
  int blk = 0;
  for (int i = 0; i < 5; ++i){
    td.d[i] = { tsr[i], tds[i], tN[i], tK[i], tc[i], tE[i], blk };
    blk += (int)(((long)tN[i]*tE[i] + 255) / 256);
  }
  transpose_cast<<<blk, 256, 0, stream>>>(td);

  // ---- 2. bf16 packed weight slices ----
  WPs wp_;
  const float* wsr[9] = { awih,  awhh,  g1whh, g2whh, wq,    wp,     wp,     g1wih,  g2wih };
  int wdo[9] = { 0,     24576, 49152, 73728, 98304, 106496, 114688, 122880, 147456 };
  int wf3[9] = { 1,     1,     1,     1,     0,     0,      0,      1,      1 };
  int wc0[9] = { 128,   0,     0,     0,     0,     0,      256,    0,      0 };
  int wsk[9] = { 384,   256,   256,   256,   256,   512,    512,    256,    256 };
  int wblk = 0;
  for (int i = 0; i < 9; ++i){
    wp_.d[i] = { wsr[i], wdo[i], wf3[i], wc0[i], wsk[i], wblk };
    wblk += (wf3[i] ? 196608 : 65536) / 256;
  }
  wpack<<<wblk, 256, 0, stream>>>(wp_, (unsigned short*)wpkf);

  // ---- 3. enc packed slices ----
  encpack<<<(B_*TE_*H_)/256, 256, 0, stream>>>(enc, (unsigned short*)encpkf);

  // ---- 4. prenet + preGI (teacher-forced, loop-invariant) ----
  gemm_k<1, true,  0><<<dim3(BT_/64, 4), 256, 0, stream>>>(tgt, 0,   w1T,    256, 400, pb1,  p1f);
  gemm_k<0, true,  0><<<dim3(BT_/64, 2), 256, 0, stream>>>(p1f, 256, w2T,    128, 256, pb2,  p2f);
  gemm_k<0, false, 0><<<dim3(BT_/64,12), 256, 0, stream>>>(p2f, 128, awihPT, 768, 128, abih, preGIf);
  // ---- 5. pm = enc @ wm.T, packed-slice bf16 store ----
  gemm_k<0, false, 3><<<dim3((B_*TE_)/64, 4), 256, 0, stream>>>(enc, 256, wmT, 256, 256, nullptr, pmpkf);

  // ---- 6. recurrence ----
  DP P;
  P.preGI = preGIf;
  P.wpk = (const uint4*)wpkf; P.pmpk = (const uint4*)pmpkf; P.encpk = (const uint4*)encpkf;
  P.abhh = abhh; P.g1bih = g1bih; P.g1bhh = g1bhh; P.g2bih = g2bih; P.g2bhh = g2bhh;
  P.bp = bp; P.v_attn = vat;
  P.decbuf = decb;
  P.aln = (float*)d_out + (size_t)BT_*OUT_;
  decoder_kernel<<<B_, 1024, 0, stream>>>(P);

  // ---- 7. deferred output projection ----
  gemm_k<0, false, 0><<<dim3(BT_/64, 7), 256, 0, stream>>>(decb, 256, woT, 400, 256, bo, (float*)d_out);
}

// Round 6
// 44811.148 us; speedup vs baseline: 3.2114x; 3.2114x over previous
//
#include <hip/hip_runtime.h>

#define B_    128
#define T_    200
#define TE_   256
#define H_    256
#define PRE_  128
#define OUT_  400
#define BT_   (B_*T_)          // 25600

__device__ __forceinline__ float sigm_(float x){ return 1.f/(1.f+__expf(-x)); }
__device__ __forceinline__ float tanh_(float x){
  x = fminf(15.f, fmaxf(-15.f, x));
  float e = __expf(2.f*x);
  return 1.f - 2.f/(e+1.f);
}
__device__ __forceinline__ float b2f_lo(unsigned u){ return __uint_as_float(u << 16); }
__device__ __forceinline__ float b2f_hi(unsigned u){ return __uint_as_float(u & 0xffff0000u); }
__device__ __forceinline__ unsigned short f2b(float f){
  unsigned u = __float_as_uint(f);
  unsigned r = (u + 0x7fff + ((u >> 16) & 1)) >> 16;   // RNE
  return (unsigned short)r;
}

// ---------------------------------------------------------------------------
// packed-weight geometry (bf16, uint4 = 8 weights along k):
//  TRIPLE slice (768-out matvec, wave-slot s): [32 oct][3 g][64 lane][8 k]
//     96 KB = 6144 uint4/slot; lane addr = oct*192 + g*64 + l
//     lane l of slot s produces cols {s*64+l, 256+s*64+l, 512+s*64+l}
//  SINGLE slice (256-out matvec, wave-slot s): [32 oct][64 lane][8 k]
//     32 KB = 2048 uint4/slot; lane addr = oct*64 + l ; col = s*64+l
// Wpk layout (uint4 offsets):
//  awihA 0 | awhh 24576 | g1whh 49152 | g2whh 73728   (4 slots x 6144)
//  wq 98304 | wpA 106496 | wpB 114688                 (4 slots x 2048)
//  g1wih 122880 | g2wih 147456                        (4 slots x 6144)
// ---------------------------------------------------------------------------

__device__ __forceinline__ void fma8(float& a, const uint4 w, const float4 xa, const float4 xb){
  a = fmaf(xa.x, b2f_lo(w.x), a); a = fmaf(xa.y, b2f_hi(w.x), a);
  a = fmaf(xa.z, b2f_lo(w.y), a); a = fmaf(xa.w, b2f_hi(w.y), a);
  a = fmaf(xb.x, b2f_lo(w.z), a); a = fmaf(xb.y, b2f_hi(w.z), a);
  a = fmaf(xb.z, b2f_lo(w.w), a); a = fmaf(xb.w, b2f_hi(w.w), a);
}

// triple matvec: p = slot base + lane. No staging arrays (rule #20).
__device__ __forceinline__ void mv3(const uint4* __restrict__ p, const float* __restrict__ x,
                                    float& o0, float& o1, float& o2)
{
  const float4* x4 = (const float4*)x;
  float a0=0.f,b0=0.f,c0=0.f, a1=0.f,b1=0.f,c1=0.f;
#pragma unroll
  for (int o = 0; o < 16; ++o){                 // 2 octs / iter
    const uint4* q = p + o*384;
    uint4 wa0=q[0],   wa1=q[64],  wa2=q[128];
    uint4 wb0=q[192], wb1=q[256], wb2=q[320];
    float4 x0=x4[o*4], x1=x4[o*4+1], x2=x4[o*4+2], x3=x4[o*4+3];
    fma8(a0,wa0,x0,x1); fma8(b0,wa1,x0,x1); fma8(c0,wa2,x0,x1);
    fma8(a1,wb0,x2,x3); fma8(b1,wb1,x2,x3); fma8(c1,wb2,x2,x3);
  }
  o0=a0+a1; o1=b0+b1; o2=c0+c1;
}

// single matvec: p = slot base + lane.
__device__ __forceinline__ float mv1(const uint4* __restrict__ p, const float* __restrict__ x)
{
  const float4* x4 = (const float4*)x;
  float a0=0.f,a1=0.f,a2=0.f,a3=0.f;
#pragma unroll
  for (int o = 0; o < 8; ++o){                  // 4 octs / iter
    const uint4* q = p + o*256;
    uint4 w0=q[0], w1=q[64], w2=q[128], w3=q[192];
    float4 x0=x4[o*8],   x1=x4[o*8+1], x2=x4[o*8+2], x3=x4[o*8+3];
    float4 x4v=x4[o*8+4],x5=x4[o*8+5], x6=x4[o*8+6], x7=x4[o*8+7];
    fma8(a0,w0,x0,x1); fma8(a1,w1,x2,x3); fma8(a2,w2,x4v,x5); fma8(a3,w3,x6,x7);
  }
  return (a0+a1)+(a2+a3);
}

// scores: lane owns one te col; e = sum_h v[h]*tanh(pm[h][te]+q[h])
__device__ __forceinline__ float mvtanh(const uint4* __restrict__ p,
                                        const float* __restrict__ qv, const float* __restrict__ vv)
{
  const float4* q4 = (const float4*)qv;
  const float4* v4 = (const float4*)vv;
  float a0=0.f,a1=0.f;
#pragma unroll
  for (int o = 0; o < 16; ++o){                 // 2 octs / iter
    const uint4* pp = p + o*128;
    uint4 w0=pp[0], w1=pp[64];
    float4 qa=q4[o*4], qb=q4[o*4+1], qc=q4[o*4+2], qd=q4[o*4+3];
    float4 va=v4[o*4], vb=v4[o*4+1], vc=v4[o*4+2], vd=v4[o*4+3];
    a0 = fmaf(va.x, tanh_(b2f_lo(w0.x)+qa.x), a0); a1 = fmaf(va.y, tanh_(b2f_hi(w0.x)+qa.y), a1);
    a0 = fmaf(va.z, tanh_(b2f_lo(w0.y)+qa.z), a0); a1 = fmaf(va.w, tanh_(b2f_hi(w0.y)+qa.w), a1);
    a0 = fmaf(vb.x, tanh_(b2f_lo(w0.z)+qb.x), a0); a1 = fmaf(vb.y, tanh_(b2f_hi(w0.z)+qb.y), a1);
    a0 = fmaf(vb.z, tanh_(b2f_lo(w0.w)+qb.z), a0); a1 = fmaf(vb.w, tanh_(b2f_hi(w0.w)+qb.w), a1);
    a0 = fmaf(vc.x, tanh_(b2f_lo(w1.x)+qc.x), a0); a1 = fmaf(vc.y, tanh_(b2f_hi(w1.x)+qc.y), a1);
    a0 = fmaf(vc.z, tanh_(b2f_lo(w1.y)+qc.z), a0); a1 = fmaf(vc.w, tanh_(b2f_hi(w1.y)+qc.w), a1);
    a0 = fmaf(vd.x, tanh_(b2f_lo(w1.z)+qd.x), a0); a1 = fmaf(vd.y, tanh_(b2f_hi(w1.z)+qd.y), a1);
    a0 = fmaf(vd.z, tanh_(b2f_lo(w1.w)+qd.z), a0); a1 = fmaf(vd.w, tanh_(b2f_hi(w1.w)+qd.w), a1);
  }
  return a0+a1;
}

// ---------------- fp32 transpose (prologue/epilogue GEMM weights) ----------------
struct TD { const float* src; float* dst; int N; int Ksrc; int col0; int Keff; int blk0; };
struct TDs { TD d[5]; };

__global__ __launch_bounds__(256) void transpose_cast(TDs P)
{
  int bid = blockIdx.x, m = 0;
#pragma unroll
  for (int i = 1; i < 5; ++i) if (bid >= P.d[i].blk0) m = i;
  TD t = P.d[m];
  long gid = (long)(bid - t.blk0)*256 + threadIdx.x;
  long nk = (long)t.N * t.Keff;
  if (gid >= nk) return;
  int k = (int)(gid / t.N);
  int j = (int)(gid % t.N);
  t.dst[(size_t)k*t.N + j] = t.src[(size_t)j*t.Ksrc + t.col0 + k];
}

// ---------------- bf16 weight repack into per-wave slices ----------------
struct WP { const float* src; int dstoff_u4; int fmt3; int col0; int srcK; int blk0; };
struct WPs { WP d[9]; };

__global__ __launch_bounds__(256) void wpack(WPs P, unsigned short* __restrict__ dst)
{
  int bid = blockIdx.x, m = 0;
#pragma unroll
  for (int i = 1; i < 9; ++i) if (bid >= P.d[i].blk0) m = i;
  WP t = P.d[m];
  int idx = (bid - t.blk0)*256 + threadIdx.x;
  int total = t.fmt3 ? 196608 : 65536;
  if (idx >= total) return;
  int kk = idx & 7, l = (idx >> 3) & 63;
  int j, k;
  if (t.fmt3){
    int g   = (idx >> 9) % 3;
    int oct = (idx / 1536) & 31;
    int s   = idx / 49152;
    j = g*256 + s*64 + l; k = oct*8 + kk;
  } else {
    int oct = (idx >> 9) & 31;
    int s   = idx >> 14;
    j = s*64 + l; k = oct*8 + kk;
  }
  dst[(size_t)t.dstoff_u4*8 + idx] = f2b(t.src[(size_t)j*t.srcK + t.col0 + k]);
}

// ---------------- enc repack: [b][slot h/64][oct te/8][64 h][8 te] bf16 ----------------
__global__ __launch_bounds__(256) void encpack(const float* __restrict__ enc, unsigned short* __restrict__ dst)
{
  size_t gid = (size_t)blockIdx.x*256 + threadIdx.x;   // 128*256*256
  int b  = (int)(gid >> 16);
  int te = (int)(gid >> 8) & 255;
  int h  = (int)gid & 255;
  float v = enc[gid];
  dst[(size_t)b*65536 + ((((h>>6)*32) + (te>>3)) << 9) + ((h&63) << 3) + (te&7)] = f2b(v);
}

// ---------------- generic tiled GEMM: C = act(A[M,K] @ WT[K,N] + bias) ----------------
// AMODE: 0 = plain fp32 (lda), 1 = teacher-forced prev-frame loader
// OUTMODE: 0 = fp32 row-major, 3 = pm packed-slice bf16 store
template<int AMODE, bool RELU, int OUTMODE>
__global__ __launch_bounds__(256) void gemm_k(const float* __restrict__ A, int lda,
                                              const float* __restrict__ WT, int N, int K,
                                              const float* __restrict__ bias,
                                              float* __restrict__ C)
{
  const int tid  = threadIdx.x;
  const int row0 = blockIdx.x * 64;
  const int n0   = blockIdx.y * 64;
  __shared__ float As[16][68];
  __shared__ float Bs[16][64];
  const int tx = tid & 15, ty = tid >> 4;
  float acc[4][4];
#pragma unroll
  for (int i = 0; i < 4; ++i)
#pragma unroll
    for (int j = 0; j < 4; ++j) acc[i][j] = 0.f;

  for (int k0 = 0; k0 < K; k0 += 16){
#pragma unroll
    for (int ll = 0; ll < 4; ++ll){
      int idx = tid + ll*256;
      int m2 = idx >> 4, kk = idx & 15;
      float v;
      if (AMODE == 1){
        int r = row0 + m2;
        int t = r % T_;
        v = (t == 0) ? 0.f : A[(size_t)(r-1)*OUT_ + k0 + kk];
      } else {
        v = A[(size_t)(row0+m2)*lda + k0 + kk];
      }
      As[kk][m2] = v;
    }
#pragma unroll
    for (int ll = 0; ll < 4; ++ll){
      int idx = tid + ll*256;
      int kk = idx >> 6, j = idx & 63;
      int jg = n0 + j;
      Bs[kk][j] = (jg < N) ? WT[(size_t)(k0+kk)*N + jg] : 0.f;
    }
    __syncthreads();
#pragma unroll
    for (int kk = 0; kk < 16; ++kk){
      float4 a4 = *(const float4*)&As[kk][ty*4];
      float4 b4 = *(const float4*)&Bs[kk][tx*4];
      acc[0][0] = fmaf(a4.x, b4.x, acc[0][0]); acc[0][1] = fmaf(a4.x, b4.y, acc[0][1]);
      acc[0][2] = fmaf(a4.x, b4.z, acc[0][2]); acc[0][3] = fmaf(a4.x, b4.w, acc[0][3]);
      acc[1][0] = fmaf(a4.y, b4.x, acc[1][0]); acc[1][1] = fmaf(a4.y, b4.y, acc[1][1]);
      acc[1][2] = fmaf(a4.y, b4.z, acc[1][2]); acc[1][3] = fmaf(a4.y, b4.w, acc[1][3]);
      acc[2][0] = fmaf(a4.z, b4.x, acc[2][0]); acc[2][1] = fmaf(a4.z, b4.y, acc[2][1]);
      acc[2][2] = fmaf(a4.z, b4.z, acc[2][2]); acc[2][3] = fmaf(a4.z, b4.w, acc[2][3]);
      acc[3][0] = fmaf(a4.w, b4.x, acc[3][0]); acc[3][1] = fmaf(a4.w, b4.y, acc[3][1]);
      acc[3][2] = fmaf(a4.w, b4.z, acc[3][2]); acc[3][3] = fmaf(a4.w, b4.w, acc[3][3]);
    }
    __syncthreads();
  }
#pragma unroll
  for (int i = 0; i < 4; ++i){
    int r = row0 + ty*4 + i;
#pragma unroll
    for (int jj = 0; jj < 4; ++jj){
      int c = n0 + tx*4 + jj;
      if (c < N){
        float v = acc[i][jj] + (bias ? bias[c] : 0.f);
        if (RELU) v = fmaxf(v, 0.f);
        if (OUTMODE == 0){
          C[(size_t)r*N + c] = v;
        } else {
          int bb = r >> 8, te = r & 255, h = c;
          ((unsigned short*)C)[(size_t)bb*65536 + ((((te>>6)*32) + (h>>3)) << 9)
                               + ((te&63) << 3) + (h&7)] = f2b(v);
        }
      }
    }
  }
}

// ---------------- persistent per-batch decoder (1024 threads, 16 waves) ----------------
struct DP {
  const float *preGI;
  const uint4 *wpk, *pmpk, *encpk;
  const float *abhh, *g1bih, *g1bhh, *g2bih, *g2bhh, *bp, *v_attn;
  float *decbuf, *aln;
};

__global__ __launch_bounds__(1024, 4) void decoder_kernel(DP P)
{
  const int tid = threadIdx.x;
  const int b = blockIdx.x;
  const int w = tid >> 6, l = tid & 63;

  __shared__ __align__(16) float s_gi[768], s_gh[768], s_g1h[768], s_g2h[768];
  __shared__ __align__(16) float s_ah[256], s_h1[256], s_h2[256], s_av[256];
  __shared__ __align__(16) float s_q[256], s_dq[256], s_dec[256], s_dec2[256];
  __shared__ __align__(16) float s_v[256], s_e[256], s_alx[256];
  __shared__ float s_red[4];

  // ---- per-wave stream segment pointers (lane folded in) ----
  const uint4* segP1  = P.wpk + (size_t)w*6144 + l;
  const uint4* segB   = nullptr;
  const uint4* segWQ  = nullptr;
  const uint4* segPM  = nullptr;
  const uint4* segWPB = nullptr;
  const uint4* segWPA = nullptr;
  const uint4* segENC = nullptr;
  if (w < 4)            segB   = P.wpk + 122880 + (size_t)w*6144 + l;
  else if (w < 8)       segB   = P.wpk + 147456 + (size_t)(w-4)*6144 + l;
  else if (w < 12){
    segWQ  = P.wpk + 98304  + (size_t)(w-8)*2048 + l;
    segWPB = P.wpk + 114688 + (size_t)(w-8)*2048 + l;
    segPM  = P.pmpk + (size_t)b*8192 + (size_t)(w-8)*2048 + l;
  } else {
    segWPA = P.wpk + 106496 + (size_t)(w-12)*2048 + l;
    segENC = P.encpk + (size_t)b*8192 + (size_t)(w-12)*2048 + l;
  }

  // ---- role biases to registers ----
  float bA0=0.f, bA1=0.f, bA2=0.f;       // P1 gh pre-act bias
  float bI0=0.f, bI1=0.f, bI2=0.f;       // gih bias (P6b / P7)
  float bP = 0.f;
  if (w >= 4 && w < 8){  int c = 64*(w-4)+l;  bA0=P.abhh[c];  bA1=P.abhh[256+c];  bA2=P.abhh[512+c];
                         bI0=P.g2bih[c]; bI1=P.g2bih[256+c]; bI2=P.g2bih[512+c]; }
  if (w >= 8 && w < 12){ int c = 64*(w-8)+l;  bA0=P.g1bhh[c]; bA1=P.g1bhh[256+c]; bA2=P.g1bhh[512+c];
                         bP = P.bp[c]; }
  if (w >= 12){          int c = 64*(w-12)+l; bA0=P.g2bhh[c]; bA1=P.g2bhh[256+c]; bA2=P.g2bhh[512+c]; }
  if (w < 4){            int c = 64*w+l;      bI0=P.g1bih[c]; bI1=P.g1bih[256+c]; bI2=P.g1bih[512+c]; }

  if (tid < 256){
    s_ah[tid]=0.f; s_h1[tid]=0.f; s_h2[tid]=0.f; s_av[tid]=0.f;
    s_v[tid] = P.v_attn[tid];
  }
  __syncthreads();

  const float* pregb = P.preGI + (size_t)b*T_*768;
  float* aln_b = P.aln    + (size_t)b*T_*TE_;
  float* dec_b = P.decbuf + (size_t)b*T_*H_;

  for (int t = 0; t < T_; ++t){
    // teacher-forced gate-input prefetch (consumed in C1)
    float pr0=0.f, pr1=0.f, pr2=0.f;
    if (tid < 256){
      const float* pg = pregb + (size_t)t*768 + tid;
      pr0 = pg[0]; pr1 = pg[256]; pr2 = pg[512];
    }

    // ==== P1: four 768-wide recurrent matvecs (col-triple per lane) ====
    {
      const float* x = (w < 4) ? s_av : (w < 8) ? s_ah : (w < 12) ? s_h1 : s_h2;
      float a0, a1, a2;
      mv3(segP1, x, a0, a1, a2);
      int c = 64*(w & 3) + l;
      if (w < 4){        s_gi[c]=a0;      s_gi[256+c]=a1;      s_gi[512+c]=a2; }
      else if (w < 8){   s_gh[c]=a0+bA0;  s_gh[256+c]=a1+bA1;  s_gh[512+c]=a2+bA2; }
      else if (w < 12){  s_g1h[c]=a0+bA0; s_g1h[256+c]=a1+bA1; s_g1h[512+c]=a2+bA2; }
      else {             s_g2h[c]=a0+bA0; s_g2h[256+c]=a1+bA1; s_g2h[512+c]=a2+bA2; }
    }
    __syncthreads();                                   // B1
    // ==== C1: attention-GRU gate ====
    if (tid < 256){
      float gi0 = s_gi[tid] + pr0, gi1 = s_gi[256+tid] + pr1, gi2 = s_gi[512+tid] + pr2;
      float gh0 = s_gh[tid], gh1 = s_gh[256+tid], gh2 = s_gh[512+tid];
      float r = sigm_(gi0+gh0), z = sigm_(gi1+gh1), n = tanh_(gi2 + r*gh2);
      s_ah[tid] = (1.f-z)*n + z*s_ah[tid];
    }
    __syncthreads();                                   // B2
    // ==== P2: wq@ah (w8-11) and wpA@ah (w12-15) ====
    if (w >= 12)      s_dq[64*(w-12)+l] = mv1(segWPA, s_ah);
    else if (w >= 8)  s_q [64*(w-8)+l]  = mv1(segWQ,  s_ah);
    __syncthreads();                                   // B3
    // ==== P3: scores (w8-11) ====
    if (w >= 8 && w < 12)
      s_e[64*(w-8)+l] = mvtanh(segPM, s_q, s_v);
    __syncthreads();                                   // B4
    // ==== SM: exp + partial sums (w12-15) ====
    if (w >= 12){
      int te = 64*(w-12)+l;
      float ex = __expf(s_e[te]);
      s_alx[te] = ex;
      float s = ex;
      for (int o = 32; o; o >>= 1) s += __shfl_down(s, o, 64);
      if (l == 0) s_red[w-12] = s;
    }
    __syncthreads();                                   // B5
    // ==== P5: context (w12-15) + alignment store (w0-3) ====
    {
      float inv_tot = 1.f / ((s_red[0]+s_red[1]) + (s_red[2]+s_red[3]));
      if (w >= 12){
        float a = mv1(segENC, s_alx);
        s_av[64*(w-12)+l] = a * inv_tot;
      } else if (w < 4){
        int te = 64*w + l;
        aln_b[(size_t)t*TE_ + te] = s_alx[te] * inv_tot;
      }
    }
    __syncthreads();                                   // B6
    // ==== P6a: dec = dq + wpB@av + bp (w8-11) ====
    if (w >= 8 && w < 12){
      float a = mv1(segWPB, s_av);
      int c = 64*(w-8)+l;
      s_dec[c] = s_dq[c] + a + bP;
    }
    __syncthreads();                                   // B7
    // ==== P6b: decoder GRU1 + residual (w0-3) ====
    if (w < 4){
      float a0, a1, a2;
      mv3(segB, s_dec, a0, a1, a2);
      int c = 64*w + l;
      float gi0 = a0+bI0, gi1 = a1+bI1, gi2 = a2+bI2;
      float r = sigm_(gi0 + s_g1h[c]), z = sigm_(gi1 + s_g1h[256+c]);
      float n = tanh_(gi2 + r*s_g1h[512+c]);
      float h1n = (1.f-z)*n + z*s_h1[c];
      s_h1[c] = h1n;
      s_dec2[c] = s_dec[c] + h1n;
    }
    __syncthreads();                                   // B8
    // ==== P7: decoder GRU2 + residual + store (w4-7) ====
    if (w >= 4 && w < 8){
      float a0, a1, a2;
      mv3(segB, s_dec2, a0, a1, a2);
      int c = 64*(w-4) + l;
      float gi0 = a0+bI0, gi1 = a1+bI1, gi2 = a2+bI2;
      float r = sigm_(gi0 + s_g2h[c]), z = sigm_(gi1 + s_g2h[256+c]);
      float n = tanh_(gi2 + r*s_g2h[512+c]);
      float h2n = (1.f-z)*n + z*s_h2[c];
      s_h2[c] = h2n;
      dec_b[(size_t)t*H_ + c] = s_dec2[c] + h2n;
    }
    __syncthreads();                                   // B9
  }
}

// ---------------- host ----------------
extern "C" void kernel_launch(void* const* d_in, const int* in_sizes, int n_in,
                              void* d_out, int out_size, void* d_ws, size_t ws_size,
                              hipStream_t stream)
{
  const float* enc   = (const float*)d_in[0];
  const float* tgt   = (const float*)d_in[1];
  const float* pw1   = (const float*)d_in[2];
  const float* pb1   = (const float*)d_in[3];
  const float* pw2   = (const float*)d_in[4];
  const float* pb2   = (const float*)d_in[5];
  const float* awih  = (const float*)d_in[6];
  const float* awhh  = (const float*)d_in[7];
  const float* abih  = (const float*)d_in[8];
  const float* abhh  = (const float*)d_in[9];
  const float* wq    = (const float*)d_in[10];
  const float* wm    = (const float*)d_in[11];
  const float* vat   = (const float*)d_in[12];
  const float* wp    = (const float*)d_in[13];
  const float* bp    = (const float*)d_in[14];
  const float* g1wih = (const float*)d_in[15];
  const float* g1whh = (const float*)d_in[16];
  const float* g1bih = (const float*)d_in[17];
  const float* g1bhh = (const float*)d_in[18];
  const float* g2wih = (const float*)d_in[19];
  const float* g2whh = (const float*)d_in[20];
  const float* g2bih = (const float*)d_in[21];
  const float* g2bhh = (const float*)d_in[22];
  const float* wo    = (const float*)d_in[23];
  const float* bo    = (const float*)d_in[24];

  float* ws = (float*)d_ws;
  size_t off = 0;
  auto alloc = [&](size_t n){ float* p = ws + off; off += (n + 3) & ~(size_t)3; return p; };

  // fp32 transposed weights (prologue/epilogue GEMMs)
  float* wmT    = alloc(65536);
  float* w1T    = alloc(102400);
  float* w2T    = alloc(32768);
  float* awihPT = alloc(98304);
  float* woT    = alloc(102400);
  // packed bf16 streams
  float* wpkf   = alloc(688128);                 // 172032 uint4
  float* pmpkf  = alloc(4194304);                // 128 * 8192 uint4
  float* encpkf = alloc(4194304);
  // fp32 activation buffers
  float* decb   = alloc((size_t)BT_*H_);         // also prenet-1 output (aliased lifetimes)
  float* p2f    = alloc((size_t)BT_*PRE_);
  float* preGIf = alloc((size_t)BT_*3*H_);
  float* p1f = decb;

  // ---- 1. fp32 transposes ----
  TDs td;
  const float* tsr[5] = { wm,  pw1, pw2, awih, wo  };
  float* tds[5]       = { wmT, w1T, w2T, awihPT, woT };
  int   tN[5]  = { 256, 256, 128, 768, 400 };
  int   tK[5]  = { 256, 400, 256, 384, 256 };
  int   tc[5]  = { 0,   0,   0,   0,   0   };
  int   tE[5]  = { 256, 400, 256, 128, 256 };
  int blk = 0;
  for (int i = 0; i < 5; ++i){
    td.d[i] = { tsr[i], tds[i], tN[i], tK[i], tc[i], tE[i], blk };
    blk += (int)(((long)tN[i]*tE[i] + 255) / 256);
  }
  transpose_cast<<<blk, 256, 0, stream>>>(td);

  // ---- 2. bf16 packed weight slices ----
  WPs wp_;
  const float* wsr[9] = { awih,  awhh,  g1whh, g2whh, wq,    wp,     wp,     g1wih,  g2wih };
  int wdo[9] = { 0,     24576, 49152, 73728, 98304, 106496, 114688, 122880, 147456 };
  int wf3[9] = { 1,     1,     1,     1,     0,     0,      0,      1,      1 };
  int wc0[9] = { 128,   0,     0,     0,     0,     0,      256,    0,      0 };
  int wsk[9] = { 384,   256,   256,   256,   256,   512,    512,    256,    256 };
  int wblk = 0;
  for (int i = 0; i < 9; ++i){
    wp_.d[i] = { wsr[i], wdo[i], wf3[i], wc0[i], wsk[i], wblk };
    wblk += (wf3[i] ? 196608 : 65536) / 256;
  }
  wpack<<<wblk, 256, 0, stream>>>(wp_, (unsigned short*)wpkf);

  // ---- 3. enc packed slices ----
  encpack<<<(B_*TE_*H_)/256, 256, 0, stream>>>(enc, (unsigned short*)encpkf);

  // ---- 4. prenet + preGI (teacher-forced, loop-invariant) ----
  gemm_k<1, true,  0><<<dim3(BT_/64, 4), 256, 0, stream>>>(tgt, 0,   w1T,    256, 400, pb1,  p1f);
  gemm_k<0, true,  0><<<dim3(BT_/64, 2), 256, 0, stream>>>(p1f, 256, w2T,    128, 256, pb2,  p2f);
  gemm_k<0, false, 0><<<dim3(BT_/64,12), 256, 0, stream>>>(p2f, 128, awihPT, 768, 128, abih, preGIf);
  // ---- 5. pm = enc @ wm.T, packed-slice bf16 store ----
  gemm_k<0, false, 3><<<dim3((B_*TE_)/64, 4), 256, 0, stream>>>(enc, 256, wmT, 256, 256, nullptr, pmpkf);

  // ---- 6. recurrence ----
  DP P;
  P.preGI = preGIf;
  P.wpk = (const uint4*)wpkf; P.pmpk = (const uint4*)pmpkf; P.encpk = (const uint4*)encpkf;
  P.abhh = abhh; P.g1bih = g1bih; P.g1bhh = g1bhh; P.g2bih = g2bih; P.g2bhh = g2bhh;
  P.bp = bp; P.v_attn = vat;
  P.decbuf = decb;
  P.aln = (float*)d_out + (size_t)BT_*OUT_;
  decoder_kernel<<<B_, 1024, 0, stream>>>(P);

  // ---- 7. deferred output projection ----
  gemm_k<0, false, 0><<<dim3(BT_/64, 7), 256, 0, stream>>>(decb, 256, woT, 400, 256, bo, (float*)d_out);
}

// Round 7
// 44610.989 us; speedup vs baseline: 3.2258x; 1.0045x over previous
//
#include <hip/hip_runtime.h>

#define B_    128
#define T_    200
#define TE_   256
#define H_    256
#define PRE_  128
#define OUT_  400
#define BT_   (B_*T_)          // 25600

__device__ __forceinline__ float sigm_(float x){ return 1.f/(1.f+__expf(-x)); }
__device__ __forceinline__ float tanh_(float x){
  x = fminf(15.f, fmaxf(-15.f, x));
  float e = __expf(2.f*x);
  return 1.f - 2.f/(e+1.f);
}
__device__ __forceinline__ float b2f_lo(unsigned u){ return __uint_as_float(u << 16); }
__device__ __forceinline__ float b2f_hi(unsigned u){ return __uint_as_float(u & 0xffff0000u); }
__device__ __forceinline__ unsigned short f2b(float f){
  unsigned u = __float_as_uint(f);
  unsigned r = (u + 0x7fff + ((u >> 16) & 1)) >> 16;   // RNE
  return (unsigned short)r;
}

__device__ __forceinline__ void fma8(float& a, const uint4 w, const float4 xa, const float4 xb){
  a = fmaf(xa.x, b2f_lo(w.x), a); a = fmaf(xa.y, b2f_hi(w.x), a);
  a = fmaf(xa.z, b2f_lo(w.y), a); a = fmaf(xa.w, b2f_hi(w.y), a);
  a = fmaf(xb.x, b2f_lo(w.z), a); a = fmaf(xb.y, b2f_hi(w.z), a);
  a = fmaf(xb.z, b2f_lo(w.w), a); a = fmaf(xb.w, b2f_hi(w.w), a);
}

// ---- async global->LDS staging (1 instr = 64 lanes x 16B = 1KB, wave-uniform LDS dest) ----
__device__ __forceinline__ void dma16(const uint4* g, uint4* s){
  __builtin_amdgcn_global_load_lds((const __attribute__((address_space(1))) unsigned int*)g,
                                   (__attribute__((address_space(3))) unsigned int*)s, 16, 0, 0);
}
#define WAIT4 asm volatile("s_waitcnt vmcnt(4)" ::: "memory")
#define WAIT0 asm volatile("s_waitcnt vmcnt(0)" ::: "memory")

// ---------------------------------------------------------------------------
// packed-weight geometry (bf16, uint4 = 8 weights along k)  [same as r6]:
//  TRIPLE slice: [32 oct][3 g][64 lane][8 k] = 6144 uint4/slot (96 KB)
//  SINGLE slice: [32 oct][64 lane][8 k]      = 2048 uint4/slot (32 KB)
// Wpk (uint4 offs): awihA 0 | awhh 24576 | g1whh 49152 | g2whh 73728
//                   wq 98304 | wpA 106496 | wpB 114688 | g1wih 122880 | g2wih 147456
// ---------------------------------------------------------------------------

// triple matvec, async-staged: 96 chunks, ring 6, ahead 4
__device__ __forceinline__ void mv3_as(const uint4* __restrict__ seg, uint4* stgw,
                                       const float* __restrict__ x, int l,
                                       float& o0, float& o1, float& o2)
{
  const float4* x4 = (const float4*)x;
#pragma unroll
  for (int i = 0; i < 4; ++i) dma16(seg + i*64 + l, stgw + i*64);
  float a0=0.f, a1=0.f, a2=0.f;
#pragma unroll
  for (int c = 0; c < 96; ++c){
    if (c < 92){ dma16(seg + (c+4)*64 + l, stgw + ((c+4)%6)*64); WAIT4; }
    else if (c == 92){ WAIT0; }
    uint4 wv = stgw[(c%6)*64 + l];
    const int oct = c/3, g = c - 3*oct;
    float4 xa = x4[oct*2], xb = x4[oct*2+1];
    if (g == 0)      fma8(a0, wv, xa, xb);
    else if (g == 1) fma8(a1, wv, xa, xb);
    else             fma8(a2, wv, xa, xb);
  }
  o0=a0; o1=a1; o2=a2;
}

// single matvec, async-staged: 32 chunks
__device__ __forceinline__ float mv1_as(const uint4* __restrict__ seg, uint4* stgw,
                                        const float* __restrict__ x, int l)
{
  const float4* x4 = (const float4*)x;
#pragma unroll
  for (int i = 0; i < 4; ++i) dma16(seg + i*64 + l, stgw + i*64);
  float a0=0.f, a1=0.f;
#pragma unroll
  for (int c = 0; c < 32; ++c){
    if (c < 28){ dma16(seg + (c+4)*64 + l, stgw + ((c+4)%6)*64); WAIT4; }
    else if (c == 28){ WAIT0; }
    uint4 wv = stgw[(c%6)*64 + l];
    float4 xa = x4[c*2], xb = x4[c*2+1];
    if (c & 1) fma8(a1, wv, xa, xb);
    else       fma8(a0, wv, xa, xb);
  }
  return a0 + a1;
}

// scores matvec, async-staged: e = sum_h v[h]*tanh(pm[h][te]+q[h]); 32 chunks
__device__ __forceinline__ float mvtanh_as(const uint4* __restrict__ seg, uint4* stgw,
                                           const float* __restrict__ qv,
                                           const float* __restrict__ vv, int l)
{
  const float4* q4 = (const float4*)qv;
  const float4* v4 = (const float4*)vv;
#pragma unroll
  for (int i = 0; i < 4; ++i) dma16(seg + i*64 + l, stgw + i*64);
  float a0=0.f, a1=0.f;
#pragma unroll
  for (int c = 0; c < 32; ++c){
    if (c < 28){ dma16(seg + (c+4)*64 + l, stgw + ((c+4)%6)*64); WAIT4; }
    else if (c == 28){ WAIT0; }
    uint4 wv = stgw[(c%6)*64 + l];
    float4 qa = q4[c*2], qb = q4[c*2+1];
    float4 va = v4[c*2], vb = v4[c*2+1];
    a0 = fmaf(va.x, tanh_(b2f_lo(wv.x)+qa.x), a0); a1 = fmaf(va.y, tanh_(b2f_hi(wv.x)+qa.y), a1);
    a0 = fmaf(va.z, tanh_(b2f_lo(wv.y)+qa.z), a0); a1 = fmaf(va.w, tanh_(b2f_hi(wv.y)+qa.w), a1);
    a0 = fmaf(vb.x, tanh_(b2f_lo(wv.z)+qb.x), a0); a1 = fmaf(vb.y, tanh_(b2f_hi(wv.z)+qb.y), a1);
    a0 = fmaf(vb.z, tanh_(b2f_lo(wv.w)+qb.z), a0); a1 = fmaf(vb.w, tanh_(b2f_hi(wv.w)+qb.w), a1);
  }
  return a0 + a1;
}

// ---------------- fp32 transpose (prologue/epilogue GEMM weights) ----------------
struct TD { const float* src; float* dst; int N; int Ksrc; int col0; int Keff; int blk0; };
struct TDs { TD d[5]; };

__global__ __launch_bounds__(256) void transpose_cast(TDs P)
{
  int bid = blockIdx.x, m = 0;
#pragma unroll
  for (int i = 1; i < 5; ++i) if (bid >= P.d[i].blk0) m = i;
  TD t = P.d[m];
  long gid = (long)(bid - t.blk0)*256 + threadIdx.x;
  long nk = (long)t.N * t.Keff;
  if (gid >= nk) return;
  int k = (int)(gid / t.N);
  int j = (int)(gid % t.N);
  t.dst[(size_t)k*t.N + j] = t.src[(size_t)j*t.Ksrc + t.col0 + k];
}

// ---------------- bf16 weight repack into per-wave slices ----------------
struct WP { const float* src; int dstoff_u4; int fmt3; int col0; int srcK; int blk0; };
struct WPs { WP d[9]; };

__global__ __launch_bounds__(256) void wpack(WPs P, unsigned short* __restrict__ dst)
{
  int bid = blockIdx.x, m = 0;
#pragma unroll
  for (int i = 1; i < 9; ++i) if (bid >= P.d[i].blk0) m = i;
  WP t = P.d[m];
  int idx = (bid - t.blk0)*256 + threadIdx.x;
  int total = t.fmt3 ? 196608 : 65536;
  if (idx >= total) return;
  int kk = idx & 7, l = (idx >> 3) & 63;
  int j, k;
  if (t.fmt3){
    int g   = (idx >> 9) % 3;
    int oct = (idx / 1536) & 31;
    int s   = idx / 49152;
    j = g*256 + s*64 + l; k = oct*8 + kk;
  } else {
    int oct = (idx >> 9) & 31;
    int s   = idx >> 14;
    j = s*64 + l; k = oct*8 + kk;
  }
  dst[(size_t)t.dstoff_u4*8 + idx] = f2b(t.src[(size_t)j*t.srcK + t.col0 + k]);
}

// ---------------- enc repack: [b][slot h/64][oct te/8][64 h][8 te] bf16 ----------------
__global__ __launch_bounds__(256) void encpack(const float* __restrict__ enc, unsigned short* __restrict__ dst)
{
  size_t gid = (size_t)blockIdx.x*256 + threadIdx.x;   // 128*256*256
  int b  = (int)(gid >> 16);
  int te = (int)(gid >> 8) & 255;
  int h  = (int)gid & 255;
  float v = enc[gid];
  dst[(size_t)b*65536 + ((((h>>6)*32) + (te>>3)) << 9) + ((h&63) << 3) + (te&7)] = f2b(v);
}

// ---------------- generic tiled GEMM: C = act(A[M,K] @ WT[K,N] + bias) ----------------
template<int AMODE, bool RELU, int OUTMODE>
__global__ __launch_bounds__(256) void gemm_k(const float* __restrict__ A, int lda,
                                              const float* __restrict__ WT, int N, int K,
                                              const float* __restrict__ bias,
                                              float* __restrict__ C)
{
  const int tid  = threadIdx.x;
  const int row0 = blockIdx.x * 64;
  const int n0   = blockIdx.y * 64;
  __shared__ float As[16][68];
  __shared__ float Bs[16][64];
  const int tx = tid & 15, ty = tid >> 4;
  float acc[4][4];
#pragma unroll
  for (int i = 0; i < 4; ++i)
#pragma unroll
    for (int j = 0; j < 4; ++j) acc[i][j] = 0.f;

  for (int k0 = 0; k0 < K; k0 += 16){
#pragma unroll
    for (int ll = 0; ll < 4; ++ll){
      int idx = tid + ll*256;
      int m2 = idx >> 4, kk = idx & 15;
      float v;
      if (AMODE == 1){
        int r = row0 + m2;
        int t = r % T_;
        v = (t == 0) ? 0.f : A[(size_t)(r-1)*OUT_ + k0 + kk];
      } else {
        v = A[(size_t)(row0+m2)*lda + k0 + kk];
      }
      As[kk][m2] = v;
    }
#pragma unroll
    for (int ll = 0; ll < 4; ++ll){
      int idx = tid + ll*256;
      int kk = idx >> 6, j = idx & 63;
      int jg = n0 + j;
      Bs[kk][j] = (jg < N) ? WT[(size_t)(k0+kk)*N + jg] : 0.f;
    }
    __syncthreads();
#pragma unroll
    for (int kk = 0; kk < 16; ++kk){
      float4 a4 = *(const float4*)&As[kk][ty*4];
      float4 b4 = *(const float4*)&Bs[kk][tx*4];
      acc[0][0] = fmaf(a4.x, b4.x, acc[0][0]); acc[0][1] = fmaf(a4.x, b4.y, acc[0][1]);
      acc[0][2] = fmaf(a4.x, b4.z, acc[0][2]); acc[0][3] = fmaf(a4.x, b4.w, acc[0][3]);
      acc[1][0] = fmaf(a4.y, b4.x, acc[1][0]); acc[1][1] = fmaf(a4.y, b4.y, acc[1][1]);
      acc[1][2] = fmaf(a4.y, b4.z, acc[1][2]); acc[1][3] = fmaf(a4.y, b4.w, acc[1][3]);
      acc[2][0] = fmaf(a4.z, b4.x, acc[2][0]); acc[2][1] = fmaf(a4.z, b4.y, acc[2][1]);
      acc[2][2] = fmaf(a4.z, b4.z, acc[2][2]); acc[2][3] = fmaf(a4.z, b4.w, acc[2][3]);
      acc[3][0] = fmaf(a4.w, b4.x, acc[3][0]); acc[3][1] = fmaf(a4.w, b4.y, acc[3][1]);
      acc[3][2] = fmaf(a4.w, b4.z, acc[3][2]); acc[3][3] = fmaf(a4.w, b4.w, acc[3][3]);
    }
    __syncthreads();
  }
#pragma unroll
  for (int i = 0; i < 4; ++i){
    int r = row0 + ty*4 + i;
#pragma unroll
    for (int jj = 0; jj < 4; ++jj){
      int c = n0 + tx*4 + jj;
      if (c < N){
        float v = acc[i][jj] + (bias ? bias[c] : 0.f);
        if (RELU) v = fmaxf(v, 0.f);
        if (OUTMODE == 0){
          C[(size_t)r*N + c] = v;
        } else {
          int bb = r >> 8, te = r & 255, h = c;
          ((unsigned short*)C)[(size_t)bb*65536 + ((((te>>6)*32) + (h>>3)) << 9)
                               + ((te&63) << 3) + (h&7)] = f2b(v);
        }
      }
    }
  }
}

// ---------------- persistent per-batch decoder (1024 threads, 16 waves) ----------------
struct DP {
  const float *preGI;
  const uint4 *wpk, *pmpk, *encpk;
  const float *abhh, *g1bih, *g1bhh, *g2bih, *g2bhh, *bp, *v_attn;
  float *decbuf, *aln;
};

__global__ __launch_bounds__(1024, 4) void decoder_kernel(DP P)
{
  const int tid = threadIdx.x;
  const int b = blockIdx.x;
  const int w = tid >> 6, l = tid & 63;

  __shared__ __align__(16) uint4 s_stg[6144];                         // 16 waves x 6 slots x 1KB = 96 KB
  __shared__ __align__(16) float s_gi[768], s_gh[768], s_g1h[768], s_g2h[768];
  __shared__ __align__(16) float s_ah[256], s_h1[256], s_h2[256], s_av[256];
  __shared__ __align__(16) float s_q[256], s_dq[256], s_dec[256], s_dec2[256];
  __shared__ __align__(16) float s_v[256], s_e[256], s_alx[256];
  __shared__ float s_red[4];

  uint4* stgw = s_stg + w*384;    // this wave's 6-slot ring

  // ---- per-wave stream segment pointers (lane folded in by the mv helpers) ----
  const uint4* segP1  = P.wpk + (size_t)w*6144;
  const uint4* segB   = nullptr;
  const uint4* segWQ  = nullptr;
  const uint4* segPM  = nullptr;
  const uint4* segWPB = nullptr;
  const uint4* segWPA = nullptr;
  const uint4* segENC = nullptr;
  if (w < 4)            segB   = P.wpk + 122880 + (size_t)w*6144;
  else if (w < 8)       segB   = P.wpk + 147456 + (size_t)(w-4)*6144;
  else if (w < 12){
    segWQ  = P.wpk + 98304  + (size_t)(w-8)*2048;
    segWPB = P.wpk + 114688 + (size_t)(w-8)*2048;
    segPM  = P.pmpk + (size_t)b*8192 + (size_t)(w-8)*2048;
  } else {
    segWPA = P.wpk + 106496 + (size_t)(w-12)*2048;
    segENC = P.encpk + (size_t)b*8192 + (size_t)(w-12)*2048;
  }

  // ---- role biases to registers ----
  float bA0=0.f, bA1=0.f, bA2=0.f;
  float bI0=0.f, bI1=0.f, bI2=0.f;
  float bP = 0.f;
  if (w >= 4 && w < 8){  int c = 64*(w-4)+l;  bA0=P.abhh[c];  bA1=P.abhh[256+c];  bA2=P.abhh[512+c];
                         bI0=P.g2bih[c]; bI1=P.g2bih[256+c]; bI2=P.g2bih[512+c]; }
  if (w >= 8 && w < 12){ int c = 64*(w-8)+l;  bA0=P.g1bhh[c]; bA1=P.g1bhh[256+c]; bA2=P.g1bhh[512+c];
                         bP = P.bp[c]; }
  if (w >= 12){          int c = 64*(w-12)+l; bA0=P.g2bhh[c]; bA1=P.g2bhh[256+c]; bA2=P.g2bhh[512+c]; }
  if (w < 4){            int c = 64*w+l;      bI0=P.g1bih[c]; bI1=P.g1bih[256+c]; bI2=P.g1bih[512+c]; }

  if (tid < 256){
    s_ah[tid]=0.f; s_h1[tid]=0.f; s_h2[tid]=0.f; s_av[tid]=0.f;
    s_v[tid] = P.v_attn[tid];
  }
  __syncthreads();

  const float* pregb = P.preGI + (size_t)b*T_*768;
  float* aln_b = P.aln    + (size_t)b*T_*TE_;
  float* dec_b = P.decbuf + (size_t)b*T_*H_;

  for (int t = 0; t < T_; ++t){
    // teacher-forced gate-input prefetch (waves 0-3); drain so phase vmcnt counts are clean
    float pr0=0.f, pr1=0.f, pr2=0.f;
    if (tid < 256){
      const float* pg = pregb + (size_t)t*768 + tid;
      pr0 = pg[0]; pr1 = pg[256]; pr2 = pg[512];
    }
    WAIT0;

    // ==== P1: four 768-wide recurrent matvecs (col-triple per lane, all 16 waves) ====
    {
      const float* x = (w < 4) ? s_av : (w < 8) ? s_ah : (w < 12) ? s_h1 : s_h2;
      float a0, a1, a2;
      mv3_as(segP1, stgw, x, l, a0, a1, a2);
      int c = 64*(w & 3) + l;
      if (w < 4){        s_gi[c]=a0;      s_gi[256+c]=a1;      s_gi[512+c]=a2; }
      else if (w < 8){   s_gh[c]=a0+bA0;  s_gh[256+c]=a1+bA1;  s_gh[512+c]=a2+bA2; }
      else if (w < 12){  s_g1h[c]=a0+bA0; s_g1h[256+c]=a1+bA1; s_g1h[512+c]=a2+bA2; }
      else {             s_g2h[c]=a0+bA0; s_g2h[256+c]=a1+bA1; s_g2h[512+c]=a2+bA2; }
    }
    __syncthreads();                                   // B1
    // ==== C1: attention-GRU gate ====
    if (tid < 256){
      float gi0 = s_gi[tid] + pr0, gi1 = s_gi[256+tid] + pr1, gi2 = s_gi[512+tid] + pr2;
      float gh0 = s_gh[tid], gh1 = s_gh[256+tid], gh2 = s_gh[512+tid];
      float r = sigm_(gi0+gh0), z = sigm_(gi1+gh1), n = tanh_(gi2 + r*gh2);
      s_ah[tid] = (1.f-z)*n + z*s_ah[tid];
    }
    __syncthreads();                                   // B2
    // ==== P2: wq@ah (w8-11) and wpA@ah (w12-15) ====
    if (w >= 12)      s_dq[64*(w-12)+l] = mv1_as(segWPA, stgw, s_ah, l);
    else if (w >= 8)  s_q [64*(w-8)+l]  = mv1_as(segWQ,  stgw, s_ah, l);
    __syncthreads();                                   // B3
    // ==== P3: scores (w8-11) ====
    if (w >= 8 && w < 12)
      s_e[64*(w-8)+l] = mvtanh_as(segPM, stgw, s_q, s_v, l);
    __syncthreads();                                   // B4
    // ==== SM: exp + partial sums (w12-15) ====
    if (w >= 12){
      int te = 64*(w-12)+l;
      float ex = __expf(s_e[te]);
      s_alx[te] = ex;
      float s = ex;
      for (int o = 32; o; o >>= 1) s += __shfl_down(s, o, 64);
      if (l == 0) s_red[w-12] = s;
    }
    __syncthreads();                                   // B5
    // ==== P5: context (w12-15) + alignment store (w0-3) ====
    {
      float inv_tot = 1.f / ((s_red[0]+s_red[1]) + (s_red[2]+s_red[3]));
      if (w >= 12){
        float a = mv1_as(segENC, stgw, s_alx, l);
        s_av[64*(w-12)+l] = a * inv_tot;
      } else if (w < 4){
        int te = 64*w + l;
        aln_b[(size_t)t*TE_ + te] = s_alx[te] * inv_tot;
      }
    }
    __syncthreads();                                   // B6
    // ==== P6a: dec = dq + wpB@av + bp (w8-11) ====
    if (w >= 8 && w < 12){
      float a = mv1_as(segWPB, stgw, s_av, l);
      int c = 64*(w-8)+l;
      s_dec[c] = s_dq[c] + a + bP;
    }
    __syncthreads();                                   // B7
    // ==== P6b: decoder GRU1 + residual (w0-3) ====
    if (w < 4){
      float a0, a1, a2;
      mv3_as(segB, stgw, s_dec, l, a0, a1, a2);
      int c = 64*w + l;
      float gi0 = a0+bI0, gi1 = a1+bI1, gi2 = a2+bI2;
      float r = sigm_(gi0 + s_g1h[c]), z = sigm_(gi1 + s_g1h[256+c]);
      float n = tanh_(gi2 + r*s_g1h[512+c]);
      float h1n = (1.f-z)*n + z*s_h1[c];
      s_h1[c] = h1n;
      s_dec2[c] = s_dec[c] + h1n;
    }
    __syncthreads();                                   // B8
    // ==== P7: decoder GRU2 + residual + store (w4-7) ====
    if (w >= 4 && w < 8){
      float a0, a1, a2;
      mv3_as(segB, stgw, s_dec2, l, a0, a1, a2);
      int c = 64*(w-4) + l;
      float gi0 = a0+bI0, gi1 = a1+bI1, gi2 = a2+bI2;
      float r = sigm_(gi0 + s_g2h[c]), z = sigm_(gi1 + s_g2h[256+c]);
      float n = tanh_(gi2 + r*s_g2h[512+c]);
      float h2n = (1.f-z)*n + z*s_h2[c];
      s_h2[c] = h2n;
      dec_b[(size_t)t*H_ + c] = s_dec2[c] + h2n;
    }
    __syncthreads();                                   // B9
  }
}

// ---------------- host ----------------
extern "C" void kernel_launch(void* const* d_in, const int* in_sizes, int n_in,
                              void* d_out, int out_size, void* d_ws, size_t ws_size,
                              hipStream_t stream)
{
  const float* enc   = (const float*)d_in[0];
  const float* tgt   = (const float*)d_in[1];
  const float* pw1   = (const float*)d_in[2];
  const float* pb1   = (const float*)d_in[3];
  const float* pw2   = (const float*)d_in[4];
  const float* pb2   = (const float*)d_in[5];
  const float* awih  = (const float*)d_in[6];
  const float* awhh  = (const float*)d_in[7];
  const float* abih  = (const float*)d_in[8];
  const float* abhh  = (const float*)d_in[9];
  const float* wq    = (const float*)d_in[10];
  const float* wm    = (const float*)d_in[11];
  const float* vat   = (const float*)d_in[12];
  const float* wp    = (const float*)d_in[13];
  const float* bp    = (const float*)d_in[14];
  const float* g1wih = (const float*)d_in[15];
  const float* g1whh = (const float*)d_in[16];
  const float* g1bih = (const float*)d_in[17];
  const float* g1bhh = (const float*)d_in[18];
  const float* g2wih = (const float*)d_in[19];
  const float* g2whh = (const float*)d_in[20];
  const float* g2bih = (const float*)d_in[21];
  const float* g2bhh = (const float*)d_in[22];
  const float* wo    = (const float*)d_in[23];
  const float* bo    = (const float*)d_in[24];

  float* ws = (float*)d_ws;
  size_t off = 0;
  auto alloc = [&](size_t n){ float* p = ws + off; off += (n + 3) & ~(size_t)3; return p; };

  float* wmT    = alloc(65536);
  float* w1T    = alloc(102400);
  float* w2T    = alloc(32768);
  float* awihPT = alloc(98304);
  float* woT    = alloc(102400);
  float* wpkf   = alloc(688128);                 // 172032 uint4
  float* pmpkf  = alloc(4194304);                // 128 * 8192 uint4
  float* encpkf = alloc(4194304);
  float* decb   = alloc((size_t)BT_*H_);
  float* p2f    = alloc((size_t)BT_*PRE_);
  float* preGIf = alloc((size_t)BT_*3*H_);
  float* p1f = decb;

  // ---- 1. fp32 transposes ----
  TDs td;
  const float* tsr[5] = { wm,  pw1, pw2, awih, wo  };
  float* tds[5]       = { wmT, w1T, w2T, awihPT, woT };
  int   tN[5]  = { 256, 256, 128, 768, 400 };
  int   tK[5]  = { 256, 400, 256, 384, 256 };
  int   tc[5]  = { 0,   0,   0,   0,   0   };
  int   tE[5]  = { 256, 400, 256, 128, 256 };
  int blk = 0;
  for (int i = 0; i < 5; ++i){
    td.d[i] = { tsr[i], tds[i], tN[i], tK[i], tc[i], tE[i], blk };
    blk += (int)(((long)tN[i]*tE[i] + 255) / 256);
  }
  transpose_cast<<<blk, 256, 0, stream>>>(td);

  // ---- 2. bf16 packed weight slices ----
  WPs wp_;
  const float* wsr[9] = { awih,  awhh,  g1whh, g2whh, wq,    wp,     wp,     g1wih,  g2wih };
  int wdo[9] = { 0,     24576, 49152, 73728, 98304, 106496, 114688, 122880, 147456 };
  int wf3[9] = { 1,     1,     1,     1,     0,     0,      0,      1,      1 };
  int wc0[9] = { 128,   0,     0,     0,     0,     0,      256,    0,      0 };
  int wsk[9] = { 384,   256,   256,   256,   256,   512,    512,    256,    256 };
  int wblk = 0;
  for (int i = 0; i < 9; ++i){
    wp_.d[i] = { wsr[i], wdo[i], wf3[i], wc0[i], wsk[i], wblk };
    wblk += (wf3[i] ? 196608 : 65536) / 256;
  }
  wpack<<<wblk, 256, 0, stream>>>(wp_, (unsigned short*)wpkf);

  // ---- 3. enc packed slices ----
  encpack<<<(B_*TE_*H_)/256, 256, 0, stream>>>(enc, (unsigned short*)encpkf);

  // ---- 4. prenet + preGI (teacher-forced, loop-invariant) ----
  gemm_k<1, true,  0><<<dim3(BT_/64, 4), 256, 0, stream>>>(tgt, 0,   w1T,    256, 400, pb1,  p1f);
  gemm_k<0, true,  0><<<dim3(BT_/64, 2), 256, 0, stream>>>(p1f, 256, w2T,    128, 256, pb2,  p2f);
  gemm_k<0, false, 0><<<dim3(BT_/64,12), 256, 0, stream>>>(p2f, 128, awihPT, 768, 128, abih, preGIf);
  // ---- 5. pm = enc @ wm.T, packed-slice bf16 store ----
  gemm_k<0, false, 3><<<dim3((B_*TE_)/64, 4), 256, 0, stream>>>(enc, 256, wmT, 256, 256, nullptr, pmpkf);

  // ---- 6. recurrence ----
  DP P;
  P.preGI = preGIf;
  P.wpk = (const uint4*)wpkf; P.pmpk = (const uint4*)pmpkf; P.encpk = (const uint4*)encpkf;
  P.abhh = abhh; P.g1bih = g1bih; P.g1bhh = g1bhh; P.g2bih = g2bih; P.g2bhh = g2bhh;
  P.bp = bp; P.v_attn = vat;
  P.decbuf = decb;
  P.aln = (float*)d_out + (size_t)BT_*OUT_;
  decoder_kernel<<<B_, 1024, 0, stream>>>(P);

  // ---- 7. deferred output projection ----
  gemm_k<0, false, 0><<<dim3(BT_/64, 7), 256, 0, stream>>>(decb, 256, woT, 400, 256, bo, (float*)d_out);
}

// Round 8
// 26920.584 us; speedup vs baseline: 5.3456x; 1.6571x over previous
//
#include <hip/hip_runtime.h>

#define B_    128
#define T_    200
#define TE_   256
#define H_    256
#define PRE_  128
#define OUT_  400
#define BT_   (B_*T_)          // 25600

__device__ __forceinline__ float sigm_(float x){ return 1.f/(1.f+__expf(-x)); }
__device__ __forceinline__ float tanh_(float x){
  x = fminf(15.f, fmaxf(-15.f, x));
  float e = __expf(2.f*x);
  return 1.f - 2.f/(e+1.f);
}
__device__ __forceinline__ float b2f_lo(unsigned u){ return __uint_as_float(u << 16); }
__device__ __forceinline__ float b2f_hi(unsigned u){ return __uint_as_float(u & 0xffff0000u); }
__device__ __forceinline__ unsigned short f2b(float f){
  unsigned u = __float_as_uint(f);
  unsigned r = (u + 0x7fff + ((u >> 16) & 1)) >> 16;   // RNE
  return (unsigned short)r;
}

// ---------------------------------------------------------------------------
// packed layouts (bf16). One uint4 = 8 bf16 = rows {2kp, 2kp+1} x 4 cols {4jq..4jq+3}.
//   u16 pos within word = (k&1)*4 + (j&3)
// TRIPLE matrix (256K x 768N):  u4 off = kp*192 + jq   (24576 u4 = 384 KB)
// SINGLE matrix (256K x 256N):  u4 off = kp*64  + jq   ( 8192 u4 = 128 KB)
// pm  packed per batch: [h-pair][te-quad]: u16 idx = b*65536 + (h>>1)*512 + (te>>2)*8 + (h&1)*4 + (te&3)
// enc packed per batch: [te-pair][h-quad]: u16 idx = b*65536 + (te>>1)*512 + (h>>2)*8 + (te&1)*4 + (h&3)
// wpk u4 offsets: awihA 0 | awhh 24576 | g1whh 49152 | g2whh 73728 |
//                 g1wih 98304 | g2wih 122880 | wq 147456 | wpA 155648 | wpB 163840
// ---------------------------------------------------------------------------

// consume one packed word: rows (x0,x1) x lane's 4 cols
__device__ __forceinline__ void pk8(float&a0,float&a1,float&a2,float&a3,
                                    const uint4 w, const float x0, const float x1){
  a0=fmaf(x0,b2f_lo(w.x),a0); a1=fmaf(x0,b2f_hi(w.x),a1);
  a2=fmaf(x0,b2f_lo(w.y),a2); a3=fmaf(x0,b2f_hi(w.y),a3);
  a0=fmaf(x1,b2f_lo(w.z),a0); a1=fmaf(x1,b2f_hi(w.z),a1);
  a2=fmaf(x1,b2f_lo(w.w),a2); a3=fmaf(x1,b2f_hi(w.w),a3);
}

// ---- 768-out matvec pair, one K-quarter (64 rows): p* pre-offset by kg*6144 + jt ----
__device__ __forceinline__ void mv768_pair(const uint4* __restrict__ pA, const uint4* __restrict__ pB,
                                           const float* __restrict__ xA, const float* __restrict__ xB,
                                           float* __restrict__ outA, float* __restrict__ outB, int jt)
{
  float A0=0,A1=0,A2=0,A3=0, B0=0,B1=0,B2=0,B3=0;
#pragma unroll
  for (int blk = 0; blk < 4; ++blk){
    const uint4* qA = pA + blk*1536;
    const uint4* qB = pB + blk*1536;
    uint4 a0=qA[0],a1=qA[192],a2=qA[384],a3=qA[576],a4=qA[768],a5=qA[960],a6=qA[1152],a7=qA[1344];
    uint4 b0=qB[0],b1=qB[192],b2=qB[384],b3=qB[576],b4=qB[768],b5=qB[960],b6=qB[1152],b7=qB[1344];
    float4 xa0=*(const float4*)(xA+blk*16),   xa1=*(const float4*)(xA+blk*16+4);
    float4 xa2=*(const float4*)(xA+blk*16+8), xa3=*(const float4*)(xA+blk*16+12);
    float4 xb0=*(const float4*)(xB+blk*16),   xb1=*(const float4*)(xB+blk*16+4);
    float4 xb2=*(const float4*)(xB+blk*16+8), xb3=*(const float4*)(xB+blk*16+12);
    pk8(A0,A1,A2,A3, a0, xa0.x,xa0.y); pk8(A0,A1,A2,A3, a1, xa0.z,xa0.w);
    pk8(A0,A1,A2,A3, a2, xa1.x,xa1.y); pk8(A0,A1,A2,A3, a3, xa1.z,xa1.w);
    pk8(A0,A1,A2,A3, a4, xa2.x,xa2.y); pk8(A0,A1,A2,A3, a5, xa2.z,xa2.w);
    pk8(A0,A1,A2,A3, a6, xa3.x,xa3.y); pk8(A0,A1,A2,A3, a7, xa3.z,xa3.w);
    pk8(B0,B1,B2,B3, b0, xb0.x,xb0.y); pk8(B0,B1,B2,B3, b1, xb0.z,xb0.w);
    pk8(B0,B1,B2,B3, b2, xb1.x,xb1.y); pk8(B0,B1,B2,B3, b3, xb1.z,xb1.w);
    pk8(B0,B1,B2,B3, b4, xb2.x,xb2.y); pk8(B0,B1,B2,B3, b5, xb2.z,xb2.w);
    pk8(B0,B1,B2,B3, b6, xb3.x,xb3.y); pk8(B0,B1,B2,B3, b7, xb3.z,xb3.w);
  }
  *(float4*)(outA + jt*4) = make_float4(A0,A1,A2,A3);
  *(float4*)(outB + jt*4) = make_float4(B0,B1,B2,B3);
}

__device__ __forceinline__ void mv768_single(const uint4* __restrict__ pA,
                                             const float* __restrict__ xA,
                                             float* __restrict__ outA, int jt)
{
  float A0=0,A1=0,A2=0,A3=0;
#pragma unroll
  for (int blk = 0; blk < 4; ++blk){
    const uint4* qA = pA + blk*1536;
    uint4 a0=qA[0],a1=qA[192],a2=qA[384],a3=qA[576],a4=qA[768],a5=qA[960],a6=qA[1152],a7=qA[1344];
    float4 xa0=*(const float4*)(xA+blk*16),   xa1=*(const float4*)(xA+blk*16+4);
    float4 xa2=*(const float4*)(xA+blk*16+8), xa3=*(const float4*)(xA+blk*16+12);
    pk8(A0,A1,A2,A3, a0, xa0.x,xa0.y); pk8(A0,A1,A2,A3, a1, xa0.z,xa0.w);
    pk8(A0,A1,A2,A3, a2, xa1.x,xa1.y); pk8(A0,A1,A2,A3, a3, xa1.z,xa1.w);
    pk8(A0,A1,A2,A3, a4, xa2.x,xa2.y); pk8(A0,A1,A2,A3, a5, xa2.z,xa2.w);
    pk8(A0,A1,A2,A3, a6, xa3.x,xa3.y); pk8(A0,A1,A2,A3, a7, xa3.z,xa3.w);
  }
  *(float4*)(outA + jt*4) = make_float4(A0,A1,A2,A3);
}

// ---- 256-out matvec pair, one K-16th (16 rows): p* pre-offset by kg*512 + jt; x pre-offset kg*16 ----
__device__ __forceinline__ void mv256_pair(const uint4* __restrict__ pA, const uint4* __restrict__ pB,
                                           const float* __restrict__ x,
                                           float* __restrict__ outA, float* __restrict__ outB, int jt)
{
  uint4 a0=pA[0],a1=pA[64],a2=pA[128],a3=pA[192],a4=pA[256],a5=pA[320],a6=pA[384],a7=pA[448];
  uint4 b0=pB[0],b1=pB[64],b2=pB[128],b3=pB[192],b4=pB[256],b5=pB[320],b6=pB[384],b7=pB[448];
  float4 x0=*(const float4*)(x), x1=*(const float4*)(x+4);
  float4 x2=*(const float4*)(x+8), x3=*(const float4*)(x+12);
  float A0=0,A1=0,A2=0,A3=0, B0=0,B1=0,B2=0,B3=0;
  pk8(A0,A1,A2,A3, a0, x0.x,x0.y); pk8(A0,A1,A2,A3, a1, x0.z,x0.w);
  pk8(A0,A1,A2,A3, a2, x1.x,x1.y); pk8(A0,A1,A2,A3, a3, x1.z,x1.w);
  pk8(A0,A1,A2,A3, a4, x2.x,x2.y); pk8(A0,A1,A2,A3, a5, x2.z,x2.w);
  pk8(A0,A1,A2,A3, a6, x3.x,x3.y); pk8(A0,A1,A2,A3, a7, x3.z,x3.w);
  pk8(B0,B1,B2,B3, b0, x0.x,x0.y); pk8(B0,B1,B2,B3, b1, x0.z,x0.w);
  pk8(B0,B1,B2,B3, b2, x1.x,x1.y); pk8(B0,B1,B2,B3, b3, x1.z,x1.w);
  pk8(B0,B1,B2,B3, b4, x2.x,x2.y); pk8(B0,B1,B2,B3, b5, x2.z,x2.w);
  pk8(B0,B1,B2,B3, b6, x3.x,x3.y); pk8(B0,B1,B2,B3, b7, x3.z,x3.w);
  *(float4*)(outA + jt*4) = make_float4(A0,A1,A2,A3);
  *(float4*)(outB + jt*4) = make_float4(B0,B1,B2,B3);
}

__device__ __forceinline__ void mv256_single(const uint4* __restrict__ pA,
                                             const float* __restrict__ x,
                                             float* __restrict__ outA, int jt)
{
  uint4 a0=pA[0],a1=pA[64],a2=pA[128],a3=pA[192],a4=pA[256],a5=pA[320],a6=pA[384],a7=pA[448];
  float4 x0=*(const float4*)(x), x1=*(const float4*)(x+4);
  float4 x2=*(const float4*)(x+8), x3=*(const float4*)(x+12);
  float A0=0,A1=0,A2=0,A3=0;
  pk8(A0,A1,A2,A3, a0, x0.x,x0.y); pk8(A0,A1,A2,A3, a1, x0.z,x0.w);
  pk8(A0,A1,A2,A3, a2, x1.x,x1.y); pk8(A0,A1,A2,A3, a3, x1.z,x1.w);
  pk8(A0,A1,A2,A3, a4, x2.x,x2.y); pk8(A0,A1,A2,A3, a5, x2.z,x2.w);
  pk8(A0,A1,A2,A3, a6, x3.x,x3.y); pk8(A0,A1,A2,A3, a7, x3.z,x3.w);
  *(float4*)(outA + jt*4) = make_float4(A0,A1,A2,A3);
}

// ---------------- fp32 transpose (prologue/epilogue GEMM weights) ----------------
struct TD { const float* src; float* dst; int N; int Ksrc; int col0; int Keff; int blk0; };
struct TDs { TD d[5]; };

__global__ __launch_bounds__(256) void transpose_cast(TDs P)
{
  int bid = blockIdx.x, m = 0;
#pragma unroll
  for (int i = 1; i < 5; ++i) if (bid >= P.d[i].blk0) m = i;
  TD t = P.d[m];
  long gid = (long)(bid - t.blk0)*256 + threadIdx.x;
  long nk = (long)t.N * t.Keff;
  if (gid >= nk) return;
  int k = (int)(gid / t.N);
  int j = (int)(gid % t.N);
  t.dst[(size_t)k*t.N + j] = t.src[(size_t)j*t.Ksrc + t.col0 + k];
}

// ---------------- bf16 weight repack into k-pair/col-quad uint4 layout ----------------
struct WP { const float* src; int dstoff_u4; int fmt3; int col0; int srcK; int blk0; };
struct WPs { WP d[9]; };

__global__ __launch_bounds__(256) void wpack(WPs P, unsigned short* __restrict__ dst)
{
  int bid = blockIdx.x, m = 0;
#pragma unroll
  for (int i = 1; i < 9; ++i) if (bid >= P.d[i].blk0) m = i;
  WP t = P.d[m];
  int idx = (bid - t.blk0)*256 + threadIdx.x;
  int total = t.fmt3 ? 196608 : 65536;
  if (idx >= total) return;
  int kp, jq, w8;
  if (t.fmt3){ kp = idx/1536; int rem = idx - kp*1536; jq = rem>>3; w8 = rem&7; }
  else       { kp = idx>>9;   int rem = idx&511;       jq = rem>>3; w8 = rem&7; }
  int k = kp*2 + (w8>>2);
  int j = jq*4 + (w8&3);
  dst[(size_t)t.dstoff_u4*8 + idx] = f2b(t.src[(size_t)j*t.srcK + t.col0 + k]);
}

// ---------------- enc repack: [b][te-pair][h-quad] bf16 ----------------
__global__ __launch_bounds__(256) void encpack(const float* __restrict__ enc, unsigned short* __restrict__ dst)
{
  size_t gid = (size_t)blockIdx.x*256 + threadIdx.x;   // 128*256*256
  int b  = (int)(gid >> 16);
  int te = (int)(gid >> 8) & 255;
  int h  = (int)gid & 255;
  float v = enc[gid];
  dst[(size_t)b*65536 + (size_t)(te>>1)*512 + (h>>2)*8 + (te&1)*4 + (h&3)] = f2b(v);
}

// ---------------- generic tiled GEMM: C = act(A[M,K] @ WT[K,N] + bias) ----------------
// AMODE: 0 = plain fp32 (lda), 1 = teacher-forced prev-frame loader
// OUTMODE: 0 = fp32 row-major, 3 = pm packed [b][h-pair][te-quad] bf16 store
template<int AMODE, bool RELU, int OUTMODE>
__global__ __launch_bounds__(256) void gemm_k(const float* __restrict__ A, int lda,
                                              const float* __restrict__ WT, int N, int K,
                                              const float* __restrict__ bias,
                                              float* __restrict__ C)
{
  const int tid  = threadIdx.x;
  const int row0 = blockIdx.x * 64;
  const int n0   = blockIdx.y * 64;
  __shared__ float As[16][68];
  __shared__ float Bs[16][64];
  const int tx = tid & 15, ty = tid >> 4;
  float acc[4][4];
#pragma unroll
  for (int i = 0; i < 4; ++i)
#pragma unroll
    for (int j = 0; j < 4; ++j) acc[i][j] = 0.f;

  for (int k0 = 0; k0 < K; k0 += 16){
#pragma unroll
    for (int ll = 0; ll < 4; ++ll){
      int idx = tid + ll*256;
      int m2 = idx >> 4, kk = idx & 15;
      float v;
      if (AMODE == 1){
        int r = row0 + m2;
        int t = r % T_;
        v = (t == 0) ? 0.f : A[(size_t)(r-1)*OUT_ + k0 + kk];
      } else {
        v = A[(size_t)(row0+m2)*lda + k0 + kk];
      }
      As[kk][m2] = v;
    }
#pragma unroll
    for (int ll = 0; ll < 4; ++ll){
      int idx = tid + ll*256;
      int kk = idx >> 6, j = idx & 63;
      int jg = n0 + j;
      Bs[kk][j] = (jg < N) ? WT[(size_t)(k0+kk)*N + jg] : 0.f;
    }
    __syncthreads();
#pragma unroll
    for (int kk = 0; kk < 16; ++kk){
      float4 a4 = *(const float4*)&As[kk][ty*4];
      float4 b4 = *(const float4*)&Bs[kk][tx*4];
      acc[0][0] = fmaf(a4.x, b4.x, acc[0][0]); acc[0][1] = fmaf(a4.x, b4.y, acc[0][1]);
      acc[0][2] = fmaf(a4.x, b4.z, acc[0][2]); acc[0][3] = fmaf(a4.x, b4.w, acc[0][3]);
      acc[1][0] = fmaf(a4.y, b4.x, acc[1][0]); acc[1][1] = fmaf(a4.y, b4.y, acc[1][1]);
      acc[1][2] = fmaf(a4.y, b4.z, acc[1][2]); acc[1][3] = fmaf(a4.y, b4.w, acc[1][3]);
      acc[2][0] = fmaf(a4.z, b4.x, acc[2][0]); acc[2][1] = fmaf(a4.z, b4.y, acc[2][1]);
      acc[2][2] = fmaf(a4.z, b4.z, acc[2][2]); acc[2][3] = fmaf(a4.z, b4.w, acc[2][3]);
      acc[3][0] = fmaf(a4.w, b4.x, acc[3][0]); acc[3][1] = fmaf(a4.w, b4.y, acc[3][1]);
      acc[3][2] = fmaf(a4.w, b4.z, acc[3][2]); acc[3][3] = fmaf(a4.w, b4.w, acc[3][3]);
    }
    __syncthreads();
  }
#pragma unroll
  for (int i = 0; i < 4; ++i){
    int r = row0 + ty*4 + i;
#pragma unroll
    for (int jj = 0; jj < 4; ++jj){
      int c = n0 + tx*4 + jj;
      if (c < N){
        float v = acc[i][jj] + (bias ? bias[c] : 0.f);
        if (RELU) v = fmaxf(v, 0.f);
        if (OUTMODE == 0){
          C[(size_t)r*N + c] = v;
        } else {
          int bb = r >> 8, te = r & 255, h = c;
          ((unsigned short*)C)[(size_t)bb*65536 + (size_t)(h>>1)*512 + (te>>2)*8
                               + (h&1)*4 + (te&3)] = f2b(v);
        }
      }
    }
  }
}

// ---------------- persistent per-batch decoder (1024 threads, 16 waves) ----------------
struct DP {
  const float *preGI;
  const uint4 *wpk, *pmpk, *encpk;
  const float *abhh, *g1bih, *g1bhh, *g2bih, *g2bhh, *bp, *v_attn;
  float *decbuf, *aln;
};

__global__ __launch_bounds__(1024, 4) void decoder_kernel(DP P)
{
  const int tid = threadIdx.x;
  const int b = blockIdx.x;

  __shared__ __align__(16) float s_part[12288];                       // 48 KB, reused per phase
  __shared__ __align__(16) float s_g1h[768], s_g2h[768];
  __shared__ __align__(16) float s_ah[H_], s_h1[H_], s_h2[H_], s_av[H_], s_dec[H_];
  __shared__ __align__(16) float s_q[H_], s_dq[H_], s_al[TE_], s_v[H_];
  __shared__ __align__(16) float s_preg[768];
  __shared__ float s_red[4];

  // biases in registers (role-dependent)
  float r_bh0=0,r_bh1=0,r_bh2=0, r_1bi0=0,r_1bi1=0,r_1bi2=0;
  float r_2bi0=0,r_2bi1=0,r_2bi2=0, r_bp=0, r_g1bh=0, r_g2bh=0;
  if (tid < H_){
    r_bh0=P.abhh[tid];  r_bh1=P.abhh[H_+tid];  r_bh2=P.abhh[2*H_+tid];
    r_1bi0=P.g1bih[tid]; r_1bi1=P.g1bih[H_+tid]; r_1bi2=P.g1bih[2*H_+tid];
    r_2bi0=P.g2bih[tid]; r_2bi1=P.g2bih[H_+tid]; r_2bi2=P.g2bih[2*H_+tid];
    r_bp=P.bp[tid];
    s_v[tid]=P.v_attn[tid];
    s_ah[tid]=0.f; s_h1[tid]=0.f; s_h2[tid]=0.f; s_av[tid]=0.f;
  } else {
    int j = tid - 256;      // 0..767
    r_g1bh = P.g1bhh[j];
    r_g2bh = P.g2bhh[j];
  }
  __syncthreads();

  const float* preg = P.preGI + (size_t)b*T_*768;
  float* aln_b = P.aln    + (size_t)b*T_*TE_;
  float* dec_b = P.decbuf + (size_t)b*T_*H_;

  // geometry
  const int kg7 = (tid < 768) ? tid/192 : 3;
  const int jt7 = (tid < 768) ? (tid - (tid/192)*192) : 0;
  const int kg8 = tid >> 6, jt8 = tid & 63;

  // pre-offset stream bases (kg + lane folded)
  const uint4* pAW = P.wpk +      0 + kg7*6144 + jt7;
  const uint4* pAH = P.wpk +  24576 + kg7*6144 + jt7;
  const uint4* pG1 = P.wpk +  49152 + kg7*6144 + jt7;
  const uint4* pG2 = P.wpk +  73728 + kg7*6144 + jt7;
  const uint4* pI1 = P.wpk +  98304 + kg7*6144 + jt7;
  const uint4* pI2 = P.wpk + 122880 + kg7*6144 + jt7;
  const uint4* pQ  = P.wpk + 147456 + kg8*512 + jt8;
  const uint4* pPA = P.wpk + 155648 + kg8*512 + jt8;
  const uint4* pPB = P.wpk + 163840 + kg8*512 + jt8;
  const uint4* pPM = P.pmpk  + (size_t)b*8192 + kg8*512 + jt8;
  const uint4* pEN = P.encpk + (size_t)b*8192 + kg8*512 + jt8;

  for (int t = 0; t < T_; ++t){
    // ==== P1: four recurrent 768-wide matvecs (768 threads) + preGI staging (256 threads) ====
    if (tid < 768){
      mv768_pair(pAW, pAH, s_av + kg7*64, s_ah + kg7*64,
                 s_part + (0*4+kg7)*768, s_part + (1*4+kg7)*768, jt7);
      mv768_pair(pG1, pG2, s_h1 + kg7*64, s_h2 + kg7*64,
                 s_part + (2*4+kg7)*768, s_part + (3*4+kg7)*768, jt7);
    } else {
      int i = tid - 768;
      s_preg[i]       = preg[(size_t)t*768 + i];
      s_preg[i + 256] = preg[(size_t)t*768 + i + 256];
      s_preg[i + 512] = preg[(size_t)t*768 + i + 512];
    }
    __syncthreads();                                    // B1
    if (tid < H_){
      float gi0 = s_part[tid]     + s_part[768+tid]     + s_part[1536+tid]     + s_part[2304+tid]     + s_preg[tid];
      float gi1 = s_part[256+tid] + s_part[1024+tid]    + s_part[1792+tid]     + s_part[2560+tid]     + s_preg[256+tid];
      float gi2 = s_part[512+tid] + s_part[1280+tid]    + s_part[2048+tid]     + s_part[2816+tid]     + s_preg[512+tid];
      float gh0 = s_part[3072+tid]     + s_part[3840+tid]     + s_part[4608+tid]     + s_part[5376+tid]     + r_bh0;
      float gh1 = s_part[3072+256+tid] + s_part[3840+256+tid] + s_part[4608+256+tid] + s_part[5376+256+tid] + r_bh1;
      float gh2 = s_part[3072+512+tid] + s_part[3840+512+tid] + s_part[4608+512+tid] + s_part[5376+512+tid] + r_bh2;
      float r = sigm_(gi0+gh0), z = sigm_(gi1+gh1), n = tanh_(gi2 + r*gh2);
      s_ah[tid] = (1.f-z)*n + z*s_ah[tid];
    } else {
      int j = tid - 256;  // 0..767
      s_g1h[j] = s_part[6144+j] + s_part[6912+j] + s_part[7680+j] + s_part[8448+j] + r_g1bh;
      s_g2h[j] = s_part[9216+j] + s_part[9984+j] + s_part[10752+j] + s_part[11520+j] + r_g2bh;
    }
    __syncthreads();                                    // B2

    // ==== P2: wq@ah and wpA@ah (all 1024 threads) ====
    mv256_pair(pQ, pPA, s_ah + kg8*16, s_part + kg8*256, s_part + 4096 + kg8*256, jt8);
    __syncthreads();                                    // B3
    if (tid < 256){
      float q = 0.f;
#pragma unroll
      for (int g = 0; g < 16; ++g) q += s_part[g*256 + tid];
      s_q[tid] = q;
    } else if (tid < 512){
      int j = tid - 256;
      float d = 0.f;
#pragma unroll
      for (int g = 0; g < 16; ++g) d += s_part[4096 + g*256 + j];
      s_dq[j] = d;
    }
    __syncthreads();                                    // B4

    // ==== P3: scores (all threads; lane owns te-quad, kg owns 16 h-rows) ====
    {
      uint4 w0=pPM[0],w1=pPM[64],w2=pPM[128],w3=pPM[192],w4=pPM[256],w5=pPM[320],w6=pPM[384],w7=pPM[448];
      float a0=0,a1=0,a2=0,a3=0;
      int h0 = kg8*16;
#define SC(wv, hh) { float q0=s_q[hh], v0=s_v[hh], q1=s_q[(hh)+1], v1=s_v[(hh)+1]; \
      a0 = fmaf(v0, tanh_(b2f_lo(wv.x)+q0), a0); a1 = fmaf(v0, tanh_(b2f_hi(wv.x)+q0), a1); \
      a2 = fmaf(v0, tanh_(b2f_lo(wv.y)+q0), a2); a3 = fmaf(v0, tanh_(b2f_hi(wv.y)+q0), a3); \
      a0 = fmaf(v1, tanh_(b2f_lo(wv.z)+q1), a0); a1 = fmaf(v1, tanh_(b2f_hi(wv.z)+q1), a1); \
      a2 = fmaf(v1, tanh_(b2f_lo(wv.w)+q1), a2); a3 = fmaf(v1, tanh_(b2f_hi(wv.w)+q1), a3); }
      SC(w0,h0) SC(w1,h0+2) SC(w2,h0+4) SC(w3,h0+6)
      SC(w4,h0+8) SC(w5,h0+10) SC(w6,h0+12) SC(w7,h0+14)
#undef SC
      *(float4*)(s_part + kg8*256 + jt8*4) = make_float4(a0,a1,a2,a3);
    }
    __syncthreads();                                    // B5
    float ex = 0.f;
    if (tid < TE_){
      float e = 0.f;
#pragma unroll
      for (int g = 0; g < 16; ++g) e += s_part[g*256 + tid];
      ex = __expf(e);
      float s = ex;
      for (int o = 32; o; o >>= 1) s += __shfl_down(s, o, 64);
      if ((tid & 63) == 0) s_red[tid >> 6] = s;
    }
    __syncthreads();                                    // B6
    if (tid < TE_){
      float s = (s_red[0]+s_red[1])+(s_red[2]+s_red[3]);
      float al = ex / s;
      s_al[tid] = al;
      aln_b[(size_t)t*TE_ + tid] = al;
    }
    __syncthreads();                                    // B7

    // ==== P4: context (all threads; lane owns h-quad, kg owns 16 te-rows) ====
    {
      uint4 w0=pEN[0],w1=pEN[64],w2=pEN[128],w3=pEN[192],w4=pEN[256],w5=pEN[320],w6=pEN[384],w7=pEN[448];
      float a0=0,a1=0,a2=0,a3=0;
      int t0 = kg8*16;
#define CT(wv, tt) { float l0=s_al[tt], l1=s_al[(tt)+1]; \
      a0 = fmaf(l0, b2f_lo(wv.x), a0); a1 = fmaf(l0, b2f_hi(wv.x), a1); \
      a2 = fmaf(l0, b2f_lo(wv.y), a2); a3 = fmaf(l0, b2f_hi(wv.y), a3); \
      a0 = fmaf(l1, b2f_lo(wv.z), a0); a1 = fmaf(l1, b2f_hi(wv.z), a1); \
      a2 = fmaf(l1, b2f_lo(wv.w), a2); a3 = fmaf(l1, b2f_hi(wv.w), a3); }
      CT(w0,t0) CT(w1,t0+2) CT(w2,t0+4) CT(w3,t0+6)
      CT(w4,t0+8) CT(w5,t0+10) CT(w6,t0+12) CT(w7,t0+14)
#undef CT
      *(float4*)(s_part + kg8*256 + jt8*4) = make_float4(a0,a1,a2,a3);
    }
    __syncthreads();                                    // B8
    if (tid < H_){
      float av = 0.f;
#pragma unroll
      for (int g = 0; g < 16; ++g) av += s_part[g*256 + tid];
      s_av[tid] = av;
    }
    __syncthreads();                                    // B9

    // ==== P5: wpB@av (all threads) ====
    mv256_single(pPB, s_av + kg8*16, s_part + kg8*256, jt8);
    __syncthreads();                                    // B10
    if (tid < H_){
      float d = s_dq[tid] + r_bp;
#pragma unroll
      for (int g = 0; g < 16; ++g) d += s_part[g*256 + tid];
      s_dec[tid] = d;
    }
    __syncthreads();                                    // B11

    // ==== P6: decoder GRU1 ====
    if (tid < 768){
      mv768_single(pI1, s_dec + kg7*64, s_part + kg7*768, jt7);
    }
    __syncthreads();                                    // B12
    if (tid < H_){
      float gi0 = s_part[tid]     + s_part[768+tid]  + s_part[1536+tid] + s_part[2304+tid] + r_1bi0;
      float gi1 = s_part[256+tid] + s_part[1024+tid] + s_part[1792+tid] + s_part[2560+tid] + r_1bi1;
      float gi2 = s_part[512+tid] + s_part[1280+tid] + s_part[2048+tid] + s_part[2816+tid] + r_1bi2;
      float r = sigm_(gi0 + s_g1h[tid]), z = sigm_(gi1 + s_g1h[256+tid]);
      float n = tanh_(gi2 + r*s_g1h[512+tid]);
      float h1n = (1.f-z)*n + z*s_h1[tid];
      s_h1[tid] = h1n;
      s_dec[tid] += h1n;
    }
    __syncthreads();                                    // B13

    // ==== P7: decoder GRU2 + store ====
    if (tid < 768){
      mv768_single(pI2, s_dec + kg7*64, s_part + kg7*768, jt7);
    }
    __syncthreads();                                    // B14
    if (tid < H_){
      float gi0 = s_part[tid]     + s_part[768+tid]  + s_part[1536+tid] + s_part[2304+tid] + r_2bi0;
      float gi1 = s_part[256+tid] + s_part[1024+tid] + s_part[1792+tid] + s_part[2560+tid] + r_2bi1;
      float gi2 = s_part[512+tid] + s_part[1280+tid] + s_part[2048+tid] + s_part[2816+tid] + r_2bi2;
      float r = sigm_(gi0 + s_g2h[tid]), z = sigm_(gi1 + s_g2h[256+tid]);
      float n = tanh_(gi2 + r*s_g2h[512+tid]);
      float h2n = (1.f-z)*n + z*s_h2[tid];
      s_h2[tid] = h2n;
      float d = s_dec[tid] + h2n;
      s_dec[tid] = d;
      dec_b[(size_t)t*H_ + tid] = d;
    }
    __syncthreads();                                    // B15
  }
}

// ---------------- host ----------------
extern "C" void kernel_launch(void* const* d_in, const int* in_sizes, int n_in,
                              void* d_out, int out_size, void* d_ws, size_t ws_size,
                              hipStream_t stream)
{
  const float* enc   = (const float*)d_in[0];
  const float* tgt   = (const float*)d_in[1];
  const float* pw1   = (const float*)d_in[2];
  const float* pb1   = (const float*)d_in[3];
  const float* pw2   = (const float*)d_in[4];
  const float* pb2   = (const float*)d_in[5];
  const float* awih  = (const float*)d_in[6];
  const float* awhh  = (const float*)d_in[7];
  const float* abih  = (const float*)d_in[8];
  const float* abhh  = (const float*)d_in[9];
  const float* wq    = (const float*)d_in[10];
  const float* wm    = (const float*)d_in[11];
  const float* vat   = (const float*)d_in[12];
  const float* wp    = (const float*)d_in[13];
  const float* bp    = (const float*)d_in[14];
  const float* g1wih = (const float*)d_in[15];
  const float* g1whh = (const float*)d_in[16];
  const float* g1bih = (const float*)d_in[17];
  const float* g1bhh = (const float*)d_in[18];
  const float* g2wih = (const float*)d_in[19];
  const float* g2whh = (const float*)d_in[20];
  const float* g2bih = (const float*)d_in[21];
  const float* g2bhh = (const float*)d_in[22];
  const float* wo    = (const float*)d_in[23];
  const float* bo    = (const float*)d_in[24];

  float* ws = (float*)d_ws;
  size_t off = 0;
  auto alloc = [&](size_t n){ float* p = ws + off; off += (n + 3) & ~(size_t)3; return p; };

  float* wmT    = alloc(65536);
  float* w1T    = alloc(102400);
  float* w2T    = alloc(32768);
  float* awihPT = alloc(98304);
  float* woT    = alloc(102400);
  float* wpkf   = alloc(688128);                 // 172032 uint4
  float* pmpkf  = alloc(4194304);                // 128 * 8192 uint4
  float* encpkf = alloc(4194304);
  float* decb   = alloc((size_t)BT_*H_);
  float* p2f    = alloc((size_t)BT_*PRE_);
  float* preGIf = alloc((size_t)BT_*3*H_);
  float* p1f = decb;

  // ---- 1. fp32 transposes ----
  TDs td;
  const float* tsr[5] = { wm,  pw1, pw2, awih, wo  };
  float* tds[5]       = { wmT, w1T, w2T, awihPT, woT };
  int   tN[5]  = { 256, 256, 128, 768, 400 };
  int   tK[5]  = { 256, 400, 256, 384, 256 };
  int   tc[5]  = { 0,   0,   0,   0,   0   };
  int   tE[5]  = { 256, 400, 256, 128, 256 };
  int blk = 0;
  for (int i = 0; i < 5; ++i){
    td.d[i] = { tsr[i], tds[i], tN[i], tK[i], tc[i], tE[i], blk };
    blk += (int)(((long)tN[i]*tE[i] + 255) / 256);
  }
  transpose_cast<<<blk, 256, 0, stream>>>(td);

  // ---- 2. bf16 packed weights (k-pair/col-quad uint4 layout) ----
  WPs wp_;
  const float* wsr[9] = { awih,  awhh,  g1whh, g2whh, g1wih, g2wih,  wq,     wp,     wp };
  int wdo[9] = { 0,     24576, 49152, 73728, 98304, 122880, 147456, 155648, 163840 };
  int wf3[9] = { 1,     1,     1,     1,     1,     1,      0,      0,      0 };
  int wc0[9] = { 128,   0,     0,     0,     0,     0,      0,      0,      256 };
  int wsk[9] = { 384,   256,   256,   256,   256,   256,    256,    512,    512 };
  int wblk = 0;
  for (int i = 0; i < 9; ++i){
    wp_.d[i] = { wsr[i], wdo[i], wf3[i], wc0[i], wsk[i], wblk };
    wblk += (wf3[i] ? 196608 : 65536) / 256;
  }
  wpack<<<wblk, 256, 0, stream>>>(wp_, (unsigned short*)wpkf);

  // ---- 3. enc packed ----
  encpack<<<(B_*TE_*H_)/256, 256, 0, stream>>>(enc, (unsigned short*)encpkf);

  // ---- 4. prenet + preGI (teacher-forced, loop-invariant) ----
  gemm_k<1, true,  0><<<dim3(BT_/64, 4), 256, 0, stream>>>(tgt, 0,   w1T,    256, 400, pb1,  p1f);
  gemm_k<0, true,  0><<<dim3(BT_/64, 2), 256, 0, stream>>>(p1f, 256, w2T,    128, 256, pb2,  p2f);
  gemm_k<0, false, 0><<<dim3(BT_/64,12), 256, 0, stream>>>(p2f, 128, awihPT, 768, 128, abih, preGIf);
  // ---- 5. pm = enc @ wm.T, packed bf16 store ----
  gemm_k<0, false, 3><<<dim3((B_*TE_)/64, 4), 256, 0, stream>>>(enc, 256, wmT, 256, 256, nullptr, pmpkf);

  // ---- 6. recurrence ----
  DP P;
  P.preGI = preGIf;
  P.wpk = (const uint4*)wpkf; P.pmpk = (const uint4*)pmpkf; P.encpk = (const uint4*)encpkf;
  P.abhh = abhh; P.g1bih = g1bih; P.g1bhh = g1bhh; P.g2bih = g2bih; P.g2bhh = g2bhh;
  P.bp = bp; P.v_attn = vat;
  P.decbuf = decb;
  P.aln = (float*)d_out + (size_t)BT_*OUT_;
  decoder_kernel<<<B_, 1024, 0, stream>>>(P);

  // ---- 7. deferred output projection ----
  gemm_k<0, false, 0><<<dim3(BT_/64, 7), 256, 0, stream>>>(decb, 256, woT, 400, 256, bo, (float*)d_out);
}